// Round 10
// baseline (152.069 us; speedup 1.0000x reference)
//
#include <hip/hip_runtime.h>

#define BS_   4
#define SEQ_  4096
#define DIM_  768
#define NH_   12
#define HD_   64
#define LK_   256

typedef __attribute__((ext_vector_type(8))) short          bf8;
typedef __attribute__((ext_vector_type(8))) unsigned short us8;
typedef __attribute__((ext_vector_type(4))) unsigned short us4;
typedef __attribute__((ext_vector_type(4))) float          f32x4;

typedef unsigned int u32g __attribute__((address_space(1)));
typedef unsigned int u32l __attribute__((address_space(3)));

#define LOG2E 1.44269504088896340736f

__device__ __forceinline__ unsigned short f2bf(float f) {
  unsigned u = __builtin_bit_cast(unsigned, f);
  u += 0x7fffu + ((u >> 16) & 1u);   // round-to-nearest-even
  return (unsigned short)(u >> 16);
}

__device__ __forceinline__ us8 cvt8(const float* __restrict__ p) {
  const float4 a = *(const float4*)p;
  const float4 b = *(const float4*)(p + 4);
  us8 r;
  r[0] = f2bf(a.x); r[1] = f2bf(a.y); r[2] = f2bf(a.z); r[3] = f2bf(a.w);
  r[4] = f2bf(b.x); r[5] = f2bf(b.y); r[6] = f2bf(b.z); r[7] = f2bf(b.w);
  return r;
}

// ---------------------------------------------------------------------------
// bf16 pre-conversion of the four 768x768 weights (query stays f32; the
// Q-proj GEMM converts it in-register during A-staging).
// ---------------------------------------------------------------------------
__global__ __launch_bounds__(256) void cvtbf_kernel(
    const float* __restrict__ Wq, const float* __restrict__ Wk,
    const float* __restrict__ Wv, const float* __restrict__ Wo,
    unsigned short* __restrict__ Wbf)
{
  const int i = blockIdx.x * 256 + threadIdx.x;   // us8 index
  const int WN8 = (DIM_ * DIM_) / 8;              // 73728
  int j = i;
  const float* src; unsigned short* dst;
  if      (j <     WN8) { src = Wq; dst = Wbf;                   }
  else if (j < 2 * WN8) { src = Wk; dst = Wbf + DIM_*DIM_;     j -=     WN8; }
  else if (j < 3 * WN8) { src = Wv; dst = Wbf + 2*DIM_*DIM_;   j -= 2 * WN8; }
  else if (j < 4 * WN8) { src = Wo; dst = Wbf + 3*DIM_*DIM_;   j -= 3 * WN8; }
  else return;
  *(us8*)(dst + (size_t)j * 8) = cvt8(src + (size_t)j * 8);
}

// ---------------------------------------------------------------------------
// Pool (float4-vectorized): 384 threads; lanes 0-191 pool key, 192-383 value.
// pooled[b,l,d] = (1/16) sum_w keep * x[b,l*16+w,d]; frac = kept/16.
// ---------------------------------------------------------------------------
__global__ __launch_bounds__(384) void pool_kernel(
    const float* __restrict__ key, const float* __restrict__ value,
    const float* __restrict__ mask,
    unsigned short* __restrict__ pk, unsigned short* __restrict__ pv,
    float* __restrict__ frac)
{
  const int blk = blockIdx.x;          // 0..1023
  const int b = blk >> 8;
  const int l = blk & 255;
  const int tid = threadIdx.x;
  __shared__ float keep[16];
  if (tid < 16) keep[tid] = (mask[b * SEQ_ + l * 16 + tid] >= 0.f) ? 1.f : 0.f;
  __syncthreads();
  const int isV = tid >= 192;
  const int c = isV ? tid - 192 : tid;            // float4 chunk 0..191
  const float* src = isV ? value : key;
  float4 acc = make_float4(0.f, 0.f, 0.f, 0.f);
  #pragma unroll 1
  for (int w = 0; w < 16; ++w) {
    if (keep[w] != 0.f) {
      const float4 v = *(const float4*)(src + (size_t)(b * SEQ_ + l * 16 + w) * DIM_ + c * 4);
      acc.x += v.x; acc.y += v.y; acc.z += v.z; acc.w += v.w;
    }
  }
  const float s = 1.f / 16.f;
  unsigned short* dst = isV ? pv : pk;
  us4 o4;
  o4[0] = f2bf(acc.x * s); o4[1] = f2bf(acc.y * s);
  o4[2] = f2bf(acc.z * s); o4[3] = f2bf(acc.w * s);
  *(us4*)(dst + (size_t)(b * LK_ + l) * DIM_ + c * 4) = o4;
  if (tid == 0) {
    float cnt = 0.f;
    for (int w = 0; w < 16; ++w) cnt += keep[w];
    frac[b * LK_ + l] = cnt * s;
  }
}

// ---------------------------------------------------------------------------
// C = A @ B^T (+ epilogue).  128x128 tile, BK=32, 4 waves, 16x16x32 bf16 MFMA.
// B (bf16) staged via global_load_lds.  SA=0: A bf16 via global_load_lds;
// SA=1: A f32, converted in-register (cvt8) then ds_write (same lane-linear
// LDS layout as the DMA path).
// SWZ: 1D grid of 768, XCD-chunked swizzle (8 XCDs x 96 blocks; consecutive
//      blocks on one XCD share the A-panel -> L2 reuse).
// MODE 0: out_bf16 = (acc + bias[c]) * scale               (Q projection)
// MODE 2: out_f32  = acc + bias[c]                         (output projection)
// MODE 34: fused K/V projection pair, blockIdx.z selects:
//   z=0 (K): acc + frac[r]*bias[c] -> Kf, key-rows permuted so the two
//            swapped-QK^T sub-tiles concatenate into the K=32 PV A-fragment.
//   z=1 (V): acc + frac[r]*bias2[c] -> Vf, K=32 B-frag order (+786432 elems).
// ---------------------------------------------------------------------------
template<int SA, int MODE, int SWZ>
__global__ __launch_bounds__(256) void gemm_bt(
    const void* __restrict__ Aptr_, const void* __restrict__ Bptr_,
    const float* __restrict__ bias, const float* __restrict__ bias2,
    const float* __restrict__ frac,
    void* __restrict__ Cout, float scale)
{
  constexpr int K = DIM_;
  __shared__ __align__(16) unsigned short lA[128 * 32];
  __shared__ __align__(16) unsigned short lB[128 * 32];
  const int tid  = threadIdx.x;
  const int lane = tid & 63;
  const int wave = tid >> 6;

  int bx, by;
  if (SWZ) {
    const int r = (blockIdx.x & 7) * 96 + (blockIdx.x >> 3);
    bx = r / 6; by = r % 6;
  } else {
    bx = blockIdx.x; by = blockIdx.y;
  }
  const int brow = bx * 128;
  const int bcol = by * 128;

  const unsigned short* A = (const unsigned short*)Aptr_;   // SA=0
  const float*          Af = (const float*)Aptr_;           // SA=1
  const unsigned short* Bw = (const unsigned short*)Bptr_;
  const float* bb = bias;
  int isV = 0;
  if (MODE == 34) {
    isV = blockIdx.z;
    A  += (size_t)isV * (BS_ * LK_ * DIM_);    // pV follows pK
    Bw += (size_t)isV * (DIM_ * DIM_);         // Wv follows Wk
    if (isV) bb = bias2;
  }

  const int wr   = (wave >> 1) * 64;
  const int wc   = (wave & 1) * 64;
  const int fr   = lane & 15;
  const int fk   = (lane >> 4) * 8;

  f32x4 acc[4][4];
  #pragma unroll
  for (int i = 0; i < 4; ++i)
    #pragma unroll
    for (int j = 0; j < 4; ++j) acc[i][j] = (f32x4){0.f, 0.f, 0.f, 0.f};

  const int srow = tid >> 2;           // 0..63
  const int schk = (tid & 3) * 8;      // k element offset

  for (int k0 = 0; k0 < K; k0 += 32) {
    us8 a0, a1;
    if (SA == 1) {
      a0 = cvt8(Af + (size_t)(brow + srow) * K + k0 + schk);
      a1 = cvt8(Af + (size_t)(brow + srow + 64) * K + k0 + schk);
    }
    __syncthreads();                   // prior reads done before overwrite
    if (SA == 0) {
      __builtin_amdgcn_global_load_lds(
          (const u32g*)(A + (size_t)(brow + srow) * K + k0 + schk),
          (u32l*)&lA[tid * 8], 16, 0, 0);
      __builtin_amdgcn_global_load_lds(
          (const u32g*)(A + (size_t)(brow + srow + 64) * K + k0 + schk),
          (u32l*)&lA[2048 + tid * 8], 16, 0, 0);
    } else {
      *(us8*)&lA[tid * 8]        = a0;
      *(us8*)&lA[2048 + tid * 8] = a1;
    }
    __builtin_amdgcn_global_load_lds(
        (const u32g*)(Bw + (size_t)(bcol + srow) * K + k0 + schk),
        (u32l*)&lB[tid * 8], 16, 0, 0);
    __builtin_amdgcn_global_load_lds(
        (const u32g*)(Bw + (size_t)(bcol + srow + 64) * K + k0 + schk),
        (u32l*)&lB[2048 + tid * 8], 16, 0, 0);
    __syncthreads();                   // drains DMA vmcnt + ds_writes
    bf8 af[4], bfv[4];
    #pragma unroll
    for (int mi = 0; mi < 4; ++mi)
      af[mi] = *(const bf8*)&lA[(wr + mi * 16 + fr) * 32 + fk];
    #pragma unroll
    for (int ni = 0; ni < 4; ++ni)
      bfv[ni] = *(const bf8*)&lB[(wc + ni * 16 + fr) * 32 + fk];
    #pragma unroll
    for (int mi = 0; mi < 4; ++mi)
      #pragma unroll
      for (int ni = 0; ni < 4; ++ni)
        acc[mi][ni] = __builtin_amdgcn_mfma_f32_16x16x32_bf16(af[mi], bfv[ni], acc[mi][ni], 0, 0, 0);
  }

  const int er = (lane >> 4) * 4;
  #pragma unroll
  for (int mi = 0; mi < 4; ++mi) {
    #pragma unroll
    for (int ni = 0; ni < 4; ++ni) {
      #pragma unroll
      for (int j = 0; j < 4; ++j) {
        const int r = brow + wr + mi * 16 + er + j;
        const int c = bcol + wc + ni * 16 + fr;
        float v = acc[mi][ni][j];
        if (MODE == 0) {
          v = (v + bias[c]) * scale;
          ((unsigned short*)Cout)[(size_t)r * DIM_ + c] = f2bf(v);
        } else if (MODE == 2) {
          ((float*)Cout)[(size_t)r * DIM_ + c] = v + bias[c];
        } else {                       // MODE 34
          v += frac[r] * bb[c];
          const int bb_ = r >> 8, key = r & 255;
          const int hh = c >> 6, dd = c & 63;
          const int bh = bb_ * NH_ + hh;
          size_t idx;
          if (isV) {
            idx = (size_t)bh * 16384 +
                ((key >> 5) * 4 + (dd >> 4)) * 512 + ((key >> 3) & 3) * 128 +
                (dd & 15) * 8 + (key & 7) + 786432;
          } else {
            const int t = key >> 5, g = (key >> 3) & 3, sub = (key >> 2) & 1, jj = key & 3;
            const int frk = g * 4 + jj;
            idx = (size_t)bh * 16384 +
                (((t * 2 + sub) * 2) + (dd >> 5)) * 512 + ((dd >> 3) & 3) * 128 +
                frk * 8 + (dd & 7);
          }
          ((unsigned short*)Cout)[idx] = f2bf(v);
        }
      }
    }
  }
}

// ---------------------------------------------------------------------------
// Fused low-rank attention — no LDS, no barriers, all 16x16x32 MFMA.
// Wave = TWO 16-row q-tiles (32 q-rows); block = 4 waves = 128 rows;
// grid 32 x 48 (6144 waves).  Each K/V fragment is loaded ONCE and feeds
// both tiles (halves L2 traffic vs 1-tile); the two tiles' softmax chains
// are independent -> they interleave and hide each other's latency.
// Softmax numerics = verified round-5 path (2^-12 floor).
// ---------------------------------------------------------------------------
__global__ __launch_bounds__(256, 2) void attn_fused(
    const unsigned short* __restrict__ Qh,   // [4,4096,768] bf16 (pre-scaled)
    const unsigned short* __restrict__ Kf,   // [48][16384] bf16 fragment-major
    const unsigned short* __restrict__ Vf,   // [48][16384] bf16 fragment-major
    unsigned short* __restrict__ ctx)        // [4,4096,768] bf16
{
  const int tid  = threadIdx.x;
  const int lane = tid & 63;
  const int wave = tid >> 6;
  const int bh = blockIdx.y;
  const int b = bh / NH_, h = bh % NH_;
  const int fr = lane & 15;
  const int hi = lane >> 4;
  const int qrow0 = blockIdx.x * 128 + wave * 32;   // tile0; tile1 = +16

  const unsigned short* qp0 = Qh + (size_t)(b * SEQ_ + qrow0 + fr) * DIM_ + h * HD_ + hi * 8;
  const unsigned short* qp1 = qp0 + 16 * DIM_;
  const bf8 q00 = *(const bf8*)qp0;
  const bf8 q01 = *(const bf8*)(qp0 + 32);
  const bf8 q10 = *(const bf8*)qp1;
  const bf8 q11 = *(const bf8*)(qp1 + 32);

  // ---- QK^T: 8 key-groups of 32; each K fragment shared by both tiles
  const unsigned short* kb = Kf + (size_t)bh * 16384 + lane * 8;
  f32x4 sA0[8], sB0[8], sA1[8], sB1[8];
  __builtin_amdgcn_s_setprio(1);
  #pragma unroll
  for (int s = 0; s < 8; ++s) {
    const bf8 ka0 = *(const bf8*)(kb + (s * 4 + 0) * 512);
    const bf8 ka1 = *(const bf8*)(kb + (s * 4 + 1) * 512);
    const bf8 kb0 = *(const bf8*)(kb + (s * 4 + 2) * 512);
    const bf8 kb1 = *(const bf8*)(kb + (s * 4 + 3) * 512);
    f32x4 x0 = (f32x4){0.f, 0.f, 0.f, 0.f};
    x0 = __builtin_amdgcn_mfma_f32_16x16x32_bf16(ka0, q00, x0, 0, 0, 0);
    x0 = __builtin_amdgcn_mfma_f32_16x16x32_bf16(ka1, q01, x0, 0, 0, 0);
    sA0[s] = x0;
    f32x4 y0 = (f32x4){0.f, 0.f, 0.f, 0.f};
    y0 = __builtin_amdgcn_mfma_f32_16x16x32_bf16(kb0, q00, y0, 0, 0, 0);
    y0 = __builtin_amdgcn_mfma_f32_16x16x32_bf16(kb1, q01, y0, 0, 0, 0);
    sB0[s] = y0;
    f32x4 x1 = (f32x4){0.f, 0.f, 0.f, 0.f};
    x1 = __builtin_amdgcn_mfma_f32_16x16x32_bf16(ka0, q10, x1, 0, 0, 0);
    x1 = __builtin_amdgcn_mfma_f32_16x16x32_bf16(ka1, q11, x1, 0, 0, 0);
    sA1[s] = x1;
    f32x4 y1 = (f32x4){0.f, 0.f, 0.f, 0.f};
    y1 = __builtin_amdgcn_mfma_f32_16x16x32_bf16(kb0, q10, y1, 0, 0, 0);
    y1 = __builtin_amdgcn_mfma_f32_16x16x32_bf16(kb1, q11, y1, 0, 0, 0);
    sB1[s] = y1;
  }
  __builtin_amdgcn_s_setprio(0);

  // ---- softmax, both tiles (independent chains interleave)
  float m0 = -1e30f, m1 = -1e30f;
  #pragma unroll
  for (int s = 0; s < 8; ++s)
    #pragma unroll
    for (int j = 0; j < 4; ++j) {
      m0 = fmaxf(m0, sA0[s][j]); m0 = fmaxf(m0, sB0[s][j]);
      m1 = fmaxf(m1, sA1[s][j]); m1 = fmaxf(m1, sB1[s][j]);
    }
  m0 = fmaxf(m0, __shfl_xor(m0, 16));
  m0 = fmaxf(m0, __shfl_xor(m0, 32));
  m1 = fmaxf(m1, __shfl_xor(m1, 16));
  m1 = fmaxf(m1, __shfl_xor(m1, 32));
  float u0 = 0.f, u1 = 0.f;
  #pragma unroll
  for (int s = 0; s < 8; ++s)
    #pragma unroll
    for (int j = 0; j < 4; ++j) {
      float p;
      p = exp2f(sA0[s][j] - m0); sA0[s][j] = p; u0 += p;
      p = exp2f(sB0[s][j] - m0); sB0[s][j] = p; u0 += p;
      p = exp2f(sA1[s][j] - m1); sA1[s][j] = p; u1 += p;
      p = exp2f(sB1[s][j] - m1); sB1[s][j] = p; u1 += p;
    }
  u0 += __shfl_xor(u0, 16);
  u0 += __shfl_xor(u0, 32);
  u1 += __shfl_xor(u1, 16);
  u1 += __shfl_xor(u1, 32);
  const float inv0 = 1.f / u0;
  const float inv1 = 1.f / u1;

  // ---- pack normalized P (RNE) into K=32 A-fragments
  bf8 pa0[8], pa1[8];
  #pragma unroll
  for (int s = 0; s < 8; ++s) {
    bf8 p0, p1;
    #pragma unroll
    for (int j = 0; j < 4; ++j) {
      p0[j]     = (short)f2bf(sA0[s][j] * inv0);
      p0[4 + j] = (short)f2bf(sB0[s][j] * inv0);
      p1[j]     = (short)f2bf(sA1[s][j] * inv1);
      p1[4 + j] = (short)f2bf(sB1[s][j] * inv1);
    }
    pa0[s] = p0; pa1[s] = p1;
  }

  // ---- PV: each V fragment loaded once, shared by both tiles
  const unsigned short* vb = Vf + (size_t)bh * 16384 + lane * 8;
  f32x4 acc0[4], acc1[4];
  #pragma unroll
  for (int ct = 0; ct < 4; ++ct) {
    acc0[ct] = (f32x4){0.f, 0.f, 0.f, 0.f};
    acc1[ct] = (f32x4){0.f, 0.f, 0.f, 0.f};
  }
  __builtin_amdgcn_s_setprio(1);
  #pragma unroll
  for (int s = 0; s < 8; ++s) {
    #pragma unroll
    for (int ct = 0; ct < 4; ++ct) {
      const bf8 vf = *(const bf8*)(vb + (s * 4 + ct) * 512);
      acc0[ct] = __builtin_amdgcn_mfma_f32_16x16x32_bf16(pa0[s], vf, acc0[ct], 0, 0, 0);
      acc1[ct] = __builtin_amdgcn_mfma_f32_16x16x32_bf16(pa1[s], vf, acc1[ct], 0, 0, 0);
    }
  }
  __builtin_amdgcn_s_setprio(0);

  // ---- ctx writes: lane holds O[q=qrow+hi*4+j][d=h*64+ct*16+fr]
  #pragma unroll
  for (int ct = 0; ct < 4; ++ct)
    #pragma unroll
    for (int j = 0; j < 4; ++j) {
      ctx[(size_t)(b * SEQ_ + qrow0 + hi * 4 + j) * DIM_ + h * HD_ + ct * 16 + fr] =
          f2bf(acc0[ct][j]);
      ctx[(size_t)(b * SEQ_ + qrow0 + 16 + hi * 4 + j) * DIM_ + h * HD_ + ct * 16 + fr] =
          f2bf(acc1[ct][j]);
    }
}

// ---------------------------------------------------------------------------
extern "C" void kernel_launch(void* const* d_in, const int* in_sizes, int n_in,
                              void* d_out, int out_size, void* d_ws, size_t ws_size,
                              hipStream_t stream) {
  const float* query = (const float*)d_in[0];
  const float* key   = (const float*)d_in[1];
  const float* value = (const float*)d_in[2];
  const float* mask  = (const float*)d_in[3];
  const float* Wq    = (const float*)d_in[4];
  const float* bq    = (const float*)d_in[5];
  const float* Wk    = (const float*)d_in[6];
  const float* bk    = (const float*)d_in[7];
  const float* Wv    = (const float*)d_in[8];
  const float* bv    = (const float*)d_in[9];
  const float* Wo    = (const float*)d_in[10];
  const float* bo    = (const float*)d_in[11];
  float* out = (float*)d_out;

  char* ws = (char*)d_ws;
  unsigned short* Qh  = (unsigned short*)ws;                  // 25,165,824 B
  unsigned short* ctx = (unsigned short*)(ws + 25165824);     // 25,165,824 B
  unsigned short* pK  = (unsigned short*)(ws + 50331648);     //  1,572,864 B
  unsigned short* pV  = (unsigned short*)(ws + 51904512);     //  1,572,864 B (pK+786432 elems)
  unsigned short* Kf  = (unsigned short*)(ws + 53477376);     //  1,572,864 B
  unsigned short* Vf  = (unsigned short*)(ws + 55050240);     //  1,572,864 B (Kf+786432 elems)
  float*          frac = (float*)(ws + 56623104);             //      4,096 B
  unsigned short* Wbf = (unsigned short*)(ws + 56627200);     //  4,718,592 B

  const float qscale = 0.125f * LOG2E;   // 1/sqrt(64), e->2 exponent base

  pool_kernel<<<dim3(1024), dim3(384), 0, stream>>>(key, value, mask, pK, pV, frac);
  cvtbf_kernel<<<dim3(1152), dim3(256), 0, stream>>>(Wq, Wk, Wv, Wo, Wbf);
  gemm_bt<1, 0, 1><<<dim3(768), dim3(256), 0, stream>>>(
      query, Wbf, bq, nullptr, nullptr, Qh, qscale);
  gemm_bt<0, 34, 0><<<dim3(8, 6, 2), dim3(256), 0, stream>>>(
      pK, Wbf + DIM_*DIM_, bk, bv, frac, Kf, 1.f);
  attn_fused<<<dim3(32, 48), dim3(256), 0, stream>>>(Qh, Kf, Vf, ctx);
  gemm_bt<0, 2, 1><<<dim3(768), dim3(256), 0, stream>>>(
      ctx, Wbf + 3*DIM_*DIM_, bo, nullptr, nullptr, out, 1.f);
}

// Round 11
// 148.995 us; speedup vs baseline: 1.0206x; 1.0206x over previous
//
#include <hip/hip_runtime.h>

#define BS_   4
#define SEQ_  4096
#define DIM_  768
#define NH_   12
#define HD_   64
#define LK_   256

typedef __attribute__((ext_vector_type(8))) short          bf8;
typedef __attribute__((ext_vector_type(8))) unsigned short us8;
typedef __attribute__((ext_vector_type(4))) unsigned short us4;
typedef __attribute__((ext_vector_type(4))) float          f32x4;

typedef unsigned int u32g __attribute__((address_space(1)));
typedef unsigned int u32l __attribute__((address_space(3)));

#define LOG2E 1.44269504088896340736f

__device__ __forceinline__ unsigned short f2bf(float f) {
  unsigned u = __builtin_bit_cast(unsigned, f);
  u += 0x7fffu + ((u >> 16) & 1u);   // round-to-nearest-even
  return (unsigned short)(u >> 16);
}

__device__ __forceinline__ us8 cvt8(const float* __restrict__ p) {
  const float4 a = *(const float4*)p;
  const float4 b = *(const float4*)(p + 4);
  us8 r;
  r[0] = f2bf(a.x); r[1] = f2bf(a.y); r[2] = f2bf(a.z); r[3] = f2bf(a.w);
  r[4] = f2bf(b.x); r[5] = f2bf(b.y); r[6] = f2bf(b.z); r[7] = f2bf(b.w);
  return r;
}

__device__ __forceinline__ f32x4 max4(f32x4 a, f32x4 b) {
  f32x4 r;
  r[0] = fmaxf(a[0], b[0]); r[1] = fmaxf(a[1], b[1]);
  r[2] = fmaxf(a[2], b[2]); r[3] = fmaxf(a[3], b[3]);
  return r;
}

// ---------------------------------------------------------------------------
// bf16 pre-conversion of the four 768x768 weights.
// ---------------------------------------------------------------------------
__global__ __launch_bounds__(256) void cvtbf_kernel(
    const float* __restrict__ Wq, const float* __restrict__ Wk,
    const float* __restrict__ Wv, const float* __restrict__ Wo,
    unsigned short* __restrict__ Wbf)
{
  const int i = blockIdx.x * 256 + threadIdx.x;   // us8 index
  const int WN8 = (DIM_ * DIM_) / 8;              // 73728
  int j = i;
  const float* src; unsigned short* dst;
  if      (j <     WN8) { src = Wq; dst = Wbf;                   }
  else if (j < 2 * WN8) { src = Wk; dst = Wbf + DIM_*DIM_;     j -=     WN8; }
  else if (j < 3 * WN8) { src = Wv; dst = Wbf + 2*DIM_*DIM_;   j -= 2 * WN8; }
  else if (j < 4 * WN8) { src = Wo; dst = Wbf + 3*DIM_*DIM_;   j -= 3 * WN8; }
  else return;
  *(us8*)(dst + (size_t)j * 8) = cvt8(src + (size_t)j * 8);
}

// ---------------------------------------------------------------------------
// Pool (float4-vectorized): 384 threads; lanes 0-191 pool key, 192-383 value.
// ---------------------------------------------------------------------------
__global__ __launch_bounds__(384) void pool_kernel(
    const float* __restrict__ key, const float* __restrict__ value,
    const float* __restrict__ mask,
    unsigned short* __restrict__ pk, unsigned short* __restrict__ pv,
    float* __restrict__ frac)
{
  const int blk = blockIdx.x;          // 0..1023
  const int b = blk >> 8;
  const int l = blk & 255;
  const int tid = threadIdx.x;
  __shared__ float keep[16];
  if (tid < 16) keep[tid] = (mask[b * SEQ_ + l * 16 + tid] >= 0.f) ? 1.f : 0.f;
  __syncthreads();
  const int isV = tid >= 192;
  const int c = isV ? tid - 192 : tid;            // float4 chunk 0..191
  const float* src = isV ? value : key;
  float4 acc = make_float4(0.f, 0.f, 0.f, 0.f);
  #pragma unroll 1
  for (int w = 0; w < 16; ++w) {
    if (keep[w] != 0.f) {
      const float4 v = *(const float4*)(src + (size_t)(b * SEQ_ + l * 16 + w) * DIM_ + c * 4);
      acc.x += v.x; acc.y += v.y; acc.z += v.z; acc.w += v.w;
    }
  }
  const float s = 1.f / 16.f;
  unsigned short* dst = isV ? pv : pk;
  us4 o4;
  o4[0] = f2bf(acc.x * s); o4[1] = f2bf(acc.y * s);
  o4[2] = f2bf(acc.z * s); o4[3] = f2bf(acc.w * s);
  *(us4*)(dst + (size_t)(b * LK_ + l) * DIM_ + c * 4) = o4;
  if (tid == 0) {
    float cnt = 0.f;
    for (int w = 0; w < 16; ++w) cnt += keep[w];
    frac[b * LK_ + l] = cnt * s;
  }
}

// ---------------------------------------------------------------------------
// Merged Q + K/V projection dispatch (864 blocks, block-uniform branch):
//  blocks 0..767  : Qh = (query@Wq^T + bq)*qscale, XCD-swizzled, A = f32
//                   query converted in-register during staging.
//  blocks 768..863: K/V pair (was its own serialized 96-block launch):
//                   kid<48 -> Kf (permuted-key K=32 A-frag layout),
//                   else   -> Vf (K=32 B-frag layout, +786432 elems).
// Core: 128x128 tile, BK=32, 4 waves, 16x16x32 bf16 MFMA, B via DMA.
// ---------------------------------------------------------------------------
__global__ __launch_bounds__(256) void gemm_qkv(
    const float* __restrict__ query, const unsigned short* __restrict__ Wbf,
    const float* __restrict__ bq, const float* __restrict__ bk,
    const float* __restrict__ bv, const float* __restrict__ frac,
    const unsigned short* __restrict__ pKV,
    unsigned short* __restrict__ Qh, unsigned short* __restrict__ KVf,
    float qscale)
{
  constexpr int K = DIM_;
  __shared__ __align__(16) unsigned short lA[128 * 32];
  __shared__ __align__(16) unsigned short lB[128 * 32];
  const int tid  = threadIdx.x;
  const int lane = tid & 63;
  const int wave = tid >> 6;
  const int bid  = blockIdx.x;
  const int isQ  = bid < 768;

  int bx, by, isV = 0;
  const unsigned short* Abf = nullptr;
  const unsigned short* Bw;
  if (isQ) {
    const int r = (bid & 7) * 96 + (bid >> 3);   // XCD-chunked swizzle
    bx = r / 6; by = r % 6;
    Bw = Wbf;
  } else {
    int kid = bid - 768;                         // 0..95
    isV = kid >= 48;
    kid -= isV * 48;
    bx = kid / 6; by = kid % 6;
    Abf = pKV + (size_t)isV * (BS_ * LK_ * DIM_);
    Bw  = Wbf + (size_t)(1 + isV) * (DIM_ * DIM_);
  }
  const int brow = bx * 128;
  const int bcol = by * 128;

  const int wr = (wave >> 1) * 64;
  const int wc = (wave & 1) * 64;
  const int fr = lane & 15;
  const int fk = (lane >> 4) * 8;

  f32x4 acc[4][4];
  #pragma unroll
  for (int i = 0; i < 4; ++i)
    #pragma unroll
    for (int j = 0; j < 4; ++j) acc[i][j] = (f32x4){0.f, 0.f, 0.f, 0.f};

  const int srow = tid >> 2;           // 0..63
  const int schk = (tid & 3) * 8;      // k element offset

  for (int k0 = 0; k0 < K; k0 += 32) {
    us8 a0, a1;
    if (isQ) {
      a0 = cvt8(query + (size_t)(brow + srow) * K + k0 + schk);
      a1 = cvt8(query + (size_t)(brow + srow + 64) * K + k0 + schk);
    }
    __syncthreads();                   // prior reads done before overwrite
    if (isQ) {
      *(us8*)&lA[tid * 8]        = a0;
      *(us8*)&lA[2048 + tid * 8] = a1;
    } else {
      __builtin_amdgcn_global_load_lds(
          (const u32g*)(Abf + (size_t)(brow + srow) * K + k0 + schk),
          (u32l*)&lA[tid * 8], 16, 0, 0);
      __builtin_amdgcn_global_load_lds(
          (const u32g*)(Abf + (size_t)(brow + srow + 64) * K + k0 + schk),
          (u32l*)&lA[2048 + tid * 8], 16, 0, 0);
    }
    __builtin_amdgcn_global_load_lds(
        (const u32g*)(Bw + (size_t)(bcol + srow) * K + k0 + schk),
        (u32l*)&lB[tid * 8], 16, 0, 0);
    __builtin_amdgcn_global_load_lds(
        (const u32g*)(Bw + (size_t)(bcol + srow + 64) * K + k0 + schk),
        (u32l*)&lB[2048 + tid * 8], 16, 0, 0);
    __syncthreads();                   // drains DMA vmcnt + ds_writes
    bf8 af[4], bfv[4];
    #pragma unroll
    for (int mi = 0; mi < 4; ++mi)
      af[mi] = *(const bf8*)&lA[(wr + mi * 16 + fr) * 32 + fk];
    #pragma unroll
    for (int ni = 0; ni < 4; ++ni)
      bfv[ni] = *(const bf8*)&lB[(wc + ni * 16 + fr) * 32 + fk];
    #pragma unroll
    for (int mi = 0; mi < 4; ++mi)
      #pragma unroll
      for (int ni = 0; ni < 4; ++ni)
        acc[mi][ni] = __builtin_amdgcn_mfma_f32_16x16x32_bf16(af[mi], bfv[ni], acc[mi][ni], 0, 0, 0);
  }

  const int er = (lane >> 4) * 4;
  #pragma unroll
  for (int mi = 0; mi < 4; ++mi) {
    #pragma unroll
    for (int ni = 0; ni < 4; ++ni) {
      #pragma unroll
      for (int j = 0; j < 4; ++j) {
        const int r = brow + wr + mi * 16 + er + j;
        const int c = bcol + wc + ni * 16 + fr;
        float v = acc[mi][ni][j];
        if (isQ) {
          v = (v + bq[c]) * qscale;
          Qh[(size_t)r * DIM_ + c] = f2bf(v);
        } else {
          v += frac[r] * (isV ? bv[c] : bk[c]);
          const int bb_ = r >> 8, key = r & 255;
          const int hh = c >> 6, dd = c & 63;
          const int bh = bb_ * NH_ + hh;
          size_t idx;
          if (isV) {
            idx = (size_t)bh * 16384 +
                ((key >> 5) * 4 + (dd >> 4)) * 512 + ((key >> 3) & 3) * 128 +
                (dd & 15) * 8 + (key & 7) + 786432;
          } else {
            const int t = key >> 5, g = (key >> 3) & 3, sub = (key >> 2) & 1, jj = key & 3;
            const int frk = g * 4 + jj;
            idx = (size_t)bh * 16384 +
                (((t * 2 + sub) * 2) + (dd >> 5)) * 512 + ((dd >> 3) & 3) * 128 +
                frk * 8 + (dd & 7);
          }
          KVf[idx] = f2bf(v);
        }
      }
    }
  }
}

// ---------------------------------------------------------------------------
// Output projection: out_f32 = ctx @ Wo^T + bo (bf16 via DMA, XCD swizzle).
// ---------------------------------------------------------------------------
__global__ __launch_bounds__(256) void gemm_out(
    const unsigned short* __restrict__ A, const unsigned short* __restrict__ Bw,
    const float* __restrict__ bias, float* __restrict__ Cout)
{
  constexpr int K = DIM_;
  __shared__ __align__(16) unsigned short lA[128 * 32];
  __shared__ __align__(16) unsigned short lB[128 * 32];
  const int tid  = threadIdx.x;
  const int lane = tid & 63;
  const int wave = tid >> 6;
  const int r0 = (blockIdx.x & 7) * 96 + (blockIdx.x >> 3);
  const int brow = (r0 / 6) * 128;
  const int bcol = (r0 % 6) * 128;
  const int wr = (wave >> 1) * 64;
  const int wc = (wave & 1) * 64;
  const int fr = lane & 15;
  const int fk = (lane >> 4) * 8;

  f32x4 acc[4][4];
  #pragma unroll
  for (int i = 0; i < 4; ++i)
    #pragma unroll
    for (int j = 0; j < 4; ++j) acc[i][j] = (f32x4){0.f, 0.f, 0.f, 0.f};

  const int srow = tid >> 2;
  const int schk = (tid & 3) * 8;

  for (int k0 = 0; k0 < K; k0 += 32) {
    __syncthreads();
    __builtin_amdgcn_global_load_lds(
        (const u32g*)(A + (size_t)(brow + srow) * K + k0 + schk),
        (u32l*)&lA[tid * 8], 16, 0, 0);
    __builtin_amdgcn_global_load_lds(
        (const u32g*)(A + (size_t)(brow + srow + 64) * K + k0 + schk),
        (u32l*)&lA[2048 + tid * 8], 16, 0, 0);
    __builtin_amdgcn_global_load_lds(
        (const u32g*)(Bw + (size_t)(bcol + srow) * K + k0 + schk),
        (u32l*)&lB[tid * 8], 16, 0, 0);
    __builtin_amdgcn_global_load_lds(
        (const u32g*)(Bw + (size_t)(bcol + srow + 64) * K + k0 + schk),
        (u32l*)&lB[2048 + tid * 8], 16, 0, 0);
    __syncthreads();
    bf8 af[4], bfv[4];
    #pragma unroll
    for (int mi = 0; mi < 4; ++mi)
      af[mi] = *(const bf8*)&lA[(wr + mi * 16 + fr) * 32 + fk];
    #pragma unroll
    for (int ni = 0; ni < 4; ++ni)
      bfv[ni] = *(const bf8*)&lB[(wc + ni * 16 + fr) * 32 + fk];
    #pragma unroll
    for (int mi = 0; mi < 4; ++mi)
      #pragma unroll
      for (int ni = 0; ni < 4; ++ni)
        acc[mi][ni] = __builtin_amdgcn_mfma_f32_16x16x32_bf16(af[mi], bfv[ni], acc[mi][ni], 0, 0, 0);
  }

  const int er = (lane >> 4) * 4;
  #pragma unroll
  for (int mi = 0; mi < 4; ++mi)
    #pragma unroll
    for (int ni = 0; ni < 4; ++ni)
      #pragma unroll
      for (int j = 0; j < 4; ++j) {
        const int r = brow + wr + mi * 16 + er + j;
        const int c = bcol + wc + ni * 16 + fr;
        Cout[(size_t)r * DIM_ + c] = acc[mi][ni][j] + bias[c];
      }
}

// ---------------------------------------------------------------------------
// Fused low-rank attention — round-9 structure (1 q-tile/wave, no LDS, no
// barriers, all 16x16x32 MFMA) + TREE reductions for softmax max/sum
// (depth ~6 instead of 64-deep serial chains; fp-max order-exact, sum
// reassociation ~1e-7 relative — 4x threshold margin).
// ---------------------------------------------------------------------------
__global__ __launch_bounds__(256) void attn_fused(
    const unsigned short* __restrict__ Qh,   // [4,4096,768] bf16 (pre-scaled)
    const unsigned short* __restrict__ Kf,   // [48][16384] bf16 fragment-major
    const unsigned short* __restrict__ Vf,   // [48][16384] bf16 fragment-major
    unsigned short* __restrict__ ctx)        // [4,4096,768] bf16
{
  const int tid  = threadIdx.x;
  const int lane = tid & 63;
  const int wave = tid >> 6;
  const int bh = blockIdx.y;
  const int b = bh / NH_, h = bh % NH_;
  const int fr = lane & 15;
  const int hi = lane >> 4;
  const int qrow = blockIdx.x * 64 + wave * 16;

  const unsigned short* qp = Qh + (size_t)(b * SEQ_ + qrow + fr) * DIM_ + h * HD_ + hi * 8;
  const bf8 q0 = *(const bf8*)qp;
  const bf8 q1 = *(const bf8*)(qp + 32);

  // ---- QK^T: 8 key-groups of 32
  const unsigned short* kb = Kf + (size_t)bh * 16384 + lane * 8;
  f32x4 scA[8], scB[8];
  __builtin_amdgcn_s_setprio(1);
  #pragma unroll
  for (int s = 0; s < 8; ++s) {
    const bf8 ka0 = *(const bf8*)(kb + (s * 4 + 0) * 512);
    const bf8 ka1 = *(const bf8*)(kb + (s * 4 + 1) * 512);
    const bf8 kb0 = *(const bf8*)(kb + (s * 4 + 2) * 512);
    const bf8 kb1 = *(const bf8*)(kb + (s * 4 + 3) * 512);
    f32x4 x = (f32x4){0.f, 0.f, 0.f, 0.f};
    x = __builtin_amdgcn_mfma_f32_16x16x32_bf16(ka0, q0, x, 0, 0, 0);
    x = __builtin_amdgcn_mfma_f32_16x16x32_bf16(ka1, q1, x, 0, 0, 0);
    scA[s] = x;
    f32x4 y = (f32x4){0.f, 0.f, 0.f, 0.f};
    y = __builtin_amdgcn_mfma_f32_16x16x32_bf16(kb0, q0, y, 0, 0, 0);
    y = __builtin_amdgcn_mfma_f32_16x16x32_bf16(kb1, q1, y, 0, 0, 0);
    scB[s] = y;
  }
  __builtin_amdgcn_s_setprio(0);

  // ---- softmax max: f32x4-elementwise tree (depth 4) + horizontal + 2 shfl
  f32x4 tm[8];
  #pragma unroll
  for (int s = 0; s < 8; ++s) tm[s] = max4(scA[s], scB[s]);
  tm[0] = max4(tm[0], tm[4]); tm[1] = max4(tm[1], tm[5]);
  tm[2] = max4(tm[2], tm[6]); tm[3] = max4(tm[3], tm[7]);
  tm[0] = max4(tm[0], tm[2]); tm[1] = max4(tm[1], tm[3]);
  tm[0] = max4(tm[0], tm[1]);
  float m = fmaxf(fmaxf(tm[0][0], tm[0][1]), fmaxf(tm[0][2], tm[0][3]));
  m = fmaxf(m, __shfl_xor(m, 16));
  m = fmaxf(m, __shfl_xor(m, 32));

  // ---- exp2 + vector partial sums (two independent 8-chains)
  f32x4 uA = (f32x4){0.f, 0.f, 0.f, 0.f};
  f32x4 uB = (f32x4){0.f, 0.f, 0.f, 0.f};
  #pragma unroll
  for (int s = 0; s < 8; ++s) {
    #pragma unroll
    for (int j = 0; j < 4; ++j) {
      scA[s][j] = exp2f(scA[s][j] - m);
      scB[s][j] = exp2f(scB[s][j] - m);
    }
    uA += scA[s];
    uB += scB[s];
  }
  const f32x4 uv = uA + uB;
  float sum = (uv[0] + uv[1]) + (uv[2] + uv[3]);
  sum += __shfl_xor(sum, 16);
  sum += __shfl_xor(sum, 32);
  const float inv = 1.f / sum;

  // ---- pack normalized P (RNE) into K=32 A-fragments
  bf8 pa[8];
  #pragma unroll
  for (int s = 0; s < 8; ++s) {
    bf8 p;
    #pragma unroll
    for (int j = 0; j < 4; ++j) {
      p[j]     = (short)f2bf(scA[s][j] * inv);
      p[4 + j] = (short)f2bf(scB[s][j] * inv);
    }
    pa[s] = p;
  }

  // ---- PV: K=256 as 8 K=32 steps, 4 d-tiles
  const unsigned short* vb = Vf + (size_t)bh * 16384 + lane * 8;
  f32x4 acc[4];
  #pragma unroll
  for (int ct = 0; ct < 4; ++ct) acc[ct] = (f32x4){0.f, 0.f, 0.f, 0.f};
  __builtin_amdgcn_s_setprio(1);
  #pragma unroll
  for (int s = 0; s < 8; ++s) {
    #pragma unroll
    for (int ct = 0; ct < 4; ++ct) {
      const bf8 vf = *(const bf8*)(vb + (s * 4 + ct) * 512);
      acc[ct] = __builtin_amdgcn_mfma_f32_16x16x32_bf16(pa[s], vf, acc[ct], 0, 0, 0);
    }
  }
  __builtin_amdgcn_s_setprio(0);

  // ---- ctx write: lane holds O[q=qrow+hi*4+j][d=h*64+ct*16+fr]
  #pragma unroll
  for (int ct = 0; ct < 4; ++ct)
    #pragma unroll
    for (int j = 0; j < 4; ++j)
      ctx[(size_t)(b * SEQ_ + qrow + hi * 4 + j) * DIM_ + h * HD_ + ct * 16 + fr] =
          f2bf(acc[ct][j]);
}

// ---------------------------------------------------------------------------
extern "C" void kernel_launch(void* const* d_in, const int* in_sizes, int n_in,
                              void* d_out, int out_size, void* d_ws, size_t ws_size,
                              hipStream_t stream) {
  const float* query = (const float*)d_in[0];
  const float* key   = (const float*)d_in[1];
  const float* value = (const float*)d_in[2];
  const float* mask  = (const float*)d_in[3];
  const float* Wq    = (const float*)d_in[4];
  const float* bq    = (const float*)d_in[5];
  const float* Wk    = (const float*)d_in[6];
  const float* bk    = (const float*)d_in[7];
  const float* Wv    = (const float*)d_in[8];
  const float* bv    = (const float*)d_in[9];
  const float* Wo    = (const float*)d_in[10];
  const float* bo    = (const float*)d_in[11];
  float* out = (float*)d_out;

  char* ws = (char*)d_ws;
  unsigned short* Qh  = (unsigned short*)ws;                  // 25,165,824 B
  unsigned short* ctx = (unsigned short*)(ws + 25165824);     // 25,165,824 B
  unsigned short* pK  = (unsigned short*)(ws + 50331648);     //  1,572,864 B
  unsigned short* pV  = (unsigned short*)(ws + 51904512);     //  1,572,864 B (pK+786432 elems)
  unsigned short* Kf  = (unsigned short*)(ws + 53477376);     //  1,572,864 B
  unsigned short* Vf  = (unsigned short*)(ws + 55050240);     //  1,572,864 B (Kf+786432 elems)
  float*          frac = (float*)(ws + 56623104);             //      4,096 B
  unsigned short* Wbf = (unsigned short*)(ws + 56627200);     //  4,718,592 B

  const float qscale = 0.125f * LOG2E;   // 1/sqrt(64), e->2 exponent base

  pool_kernel<<<dim3(1024), dim3(384), 0, stream>>>(key, value, mask, pK, pV, frac);
  cvtbf_kernel<<<dim3(1152), dim3(256), 0, stream>>>(Wq, Wk, Wv, Wo, Wbf);
  gemm_qkv<<<dim3(864), dim3(256), 0, stream>>>(
      query, Wbf, bq, bk, bv, frac, pK, Qh, Kf, qscale);
  attn_fused<<<dim3(64, 48), dim3(256), 0, stream>>>(Qh, Kf, Vf, ctx);
  gemm_out<<<dim3(768), dim3(256), 0, stream>>>(ctx, Wbf + 3*DIM_*DIM_, bo, out);
}

// Round 12
// 138.610 us; speedup vs baseline: 1.0971x; 1.0749x over previous
//
#include <hip/hip_runtime.h>

#define BS_   4
#define SEQ_  4096
#define DIM_  768
#define NH_   12
#define HD_   64
#define LK_   256

typedef __attribute__((ext_vector_type(8))) short          bf8;
typedef __attribute__((ext_vector_type(8))) unsigned short us8;
typedef __attribute__((ext_vector_type(4))) unsigned short us4;
typedef __attribute__((ext_vector_type(4))) float          f32x4;

typedef unsigned int u32g __attribute__((address_space(1)));
typedef unsigned int u32l __attribute__((address_space(3)));

#define LOG2E 1.44269504088896340736f

__device__ __forceinline__ unsigned short f2bf(float f) {
  unsigned u = __builtin_bit_cast(unsigned, f);
  u += 0x7fffu + ((u >> 16) & 1u);   // round-to-nearest-even
  return (unsigned short)(u >> 16);
}

__device__ __forceinline__ us8 cvt8(const float* __restrict__ p) {
  const float4 a = *(const float4*)p;
  const float4 b = *(const float4*)(p + 4);
  us8 r;
  r[0] = f2bf(a.x); r[1] = f2bf(a.y); r[2] = f2bf(a.z); r[3] = f2bf(a.w);
  r[4] = f2bf(b.x); r[5] = f2bf(b.y); r[6] = f2bf(b.z); r[7] = f2bf(b.w);
  return r;
}

__device__ __forceinline__ f32x4 max4(f32x4 a, f32x4 b) {
  f32x4 r;
  r[0] = fmaxf(a[0], b[0]); r[1] = fmaxf(a[1], b[1]);
  r[2] = fmaxf(a[2], b[2]); r[3] = fmaxf(a[3], b[3]);
  return r;
}

// ---------------------------------------------------------------------------
// bf16 pre-conversion of the four 768x768 weights (query stays f32; the
// Q-proj GEMM converts it in-register during A-staging).
// ---------------------------------------------------------------------------
__global__ __launch_bounds__(256) void cvtbf_kernel(
    const float* __restrict__ Wq, const float* __restrict__ Wk,
    const float* __restrict__ Wv, const float* __restrict__ Wo,
    unsigned short* __restrict__ Wbf)
{
  const int i = blockIdx.x * 256 + threadIdx.x;   // us8 index
  const int WN8 = (DIM_ * DIM_) / 8;              // 73728
  int j = i;
  const float* src; unsigned short* dst;
  if      (j <     WN8) { src = Wq; dst = Wbf;                   }
  else if (j < 2 * WN8) { src = Wk; dst = Wbf + DIM_*DIM_;     j -=     WN8; }
  else if (j < 3 * WN8) { src = Wv; dst = Wbf + 2*DIM_*DIM_;   j -= 2 * WN8; }
  else if (j < 4 * WN8) { src = Wo; dst = Wbf + 3*DIM_*DIM_;   j -= 3 * WN8; }
  else return;
  *(us8*)(dst + (size_t)j * 8) = cvt8(src + (size_t)j * 8);
}

// ---------------------------------------------------------------------------
// Pool (float4-vectorized): 384 threads; lanes 0-191 pool key, 192-383 value.
// ---------------------------------------------------------------------------
__global__ __launch_bounds__(384) void pool_kernel(
    const float* __restrict__ key, const float* __restrict__ value,
    const float* __restrict__ mask,
    unsigned short* __restrict__ pk, unsigned short* __restrict__ pv,
    float* __restrict__ frac)
{
  const int blk = blockIdx.x;          // 0..1023
  const int b = blk >> 8;
  const int l = blk & 255;
  const int tid = threadIdx.x;
  __shared__ float keep[16];
  if (tid < 16) keep[tid] = (mask[b * SEQ_ + l * 16 + tid] >= 0.f) ? 1.f : 0.f;
  __syncthreads();
  const int isV = tid >= 192;
  const int c = isV ? tid - 192 : tid;            // float4 chunk 0..191
  const float* src = isV ? value : key;
  float4 acc = make_float4(0.f, 0.f, 0.f, 0.f);
  #pragma unroll 1
  for (int w = 0; w < 16; ++w) {
    if (keep[w] != 0.f) {
      const float4 v = *(const float4*)(src + (size_t)(b * SEQ_ + l * 16 + w) * DIM_ + c * 4);
      acc.x += v.x; acc.y += v.y; acc.z += v.z; acc.w += v.w;
    }
  }
  const float s = 1.f / 16.f;
  unsigned short* dst = isV ? pv : pk;
  us4 o4;
  o4[0] = f2bf(acc.x * s); o4[1] = f2bf(acc.y * s);
  o4[2] = f2bf(acc.z * s); o4[3] = f2bf(acc.w * s);
  *(us4*)(dst + (size_t)(b * LK_ + l) * DIM_ + c * 4) = o4;
  if (tid == 0) {
    float cnt = 0.f;
    for (int w = 0; w < 16; ++w) cnt += keep[w];
    frac[b * LK_ + l] = cnt * s;
  }
}

// ---------------------------------------------------------------------------
// C = A @ B^T (+ epilogue).  128x128 tile, BK=32, 4 waves, 16x16x32 bf16 MFMA.
// TEMPLATE-specialized staging (round-11 lesson: a runtime branch here
// defeats the compiler's load pipelining — 2.7x slowdown).
// SA=0: A bf16 via global_load_lds; SA=1: A f32, cvt8 in-register + ds_write.
// SWZ: 1D grid of 768, XCD-chunked swizzle.
// MODE 0: out_bf16 = (acc + bias[c]) * scale               (Q projection)
// MODE 2: out_f32  = acc + bias[c]                         (output projection)
// MODE 34: fused K/V projection pair, blockIdx.z selects:
//   z=0 (K): acc + frac[r]*bias[c] -> Kf, key-rows permuted so the two
//            swapped-QK^T sub-tiles concatenate into the K=32 PV A-fragment.
//   z=1 (V): acc + frac[r]*bias2[c] -> Vf, K=32 B-frag order (+786432 elems).
// ---------------------------------------------------------------------------
template<int SA, int MODE, int SWZ>
__global__ __launch_bounds__(256) void gemm_bt(
    const void* __restrict__ Aptr_, const void* __restrict__ Bptr_,
    const float* __restrict__ bias, const float* __restrict__ bias2,
    const float* __restrict__ frac,
    void* __restrict__ Cout, float scale)
{
  constexpr int K = DIM_;
  __shared__ __align__(16) unsigned short lA[128 * 32];
  __shared__ __align__(16) unsigned short lB[128 * 32];
  const int tid  = threadIdx.x;
  const int lane = tid & 63;
  const int wave = tid >> 6;

  int bx, by;
  if (SWZ) {
    const int r = (blockIdx.x & 7) * 96 + (blockIdx.x >> 3);
    bx = r / 6; by = r % 6;
  } else {
    bx = blockIdx.x; by = blockIdx.y;
  }
  const int brow = bx * 128;
  const int bcol = by * 128;

  const unsigned short* A = (const unsigned short*)Aptr_;   // SA=0
  const float*          Af = (const float*)Aptr_;           // SA=1
  const unsigned short* Bw = (const unsigned short*)Bptr_;
  const float* bb = bias;
  int isV = 0;
  if (MODE == 34) {
    isV = blockIdx.z;
    A  += (size_t)isV * (BS_ * LK_ * DIM_);    // pV follows pK
    Bw += (size_t)isV * (DIM_ * DIM_);         // Wv follows Wk
    if (isV) bb = bias2;
  }

  const int wr   = (wave >> 1) * 64;
  const int wc   = (wave & 1) * 64;
  const int fr   = lane & 15;
  const int fk   = (lane >> 4) * 8;

  f32x4 acc[4][4];
  #pragma unroll
  for (int i = 0; i < 4; ++i)
    #pragma unroll
    for (int j = 0; j < 4; ++j) acc[i][j] = (f32x4){0.f, 0.f, 0.f, 0.f};

  const int srow = tid >> 2;           // 0..63
  const int schk = (tid & 3) * 8;      // k element offset

  for (int k0 = 0; k0 < K; k0 += 32) {
    us8 a0, a1;
    if (SA == 1) {
      a0 = cvt8(Af + (size_t)(brow + srow) * K + k0 + schk);
      a1 = cvt8(Af + (size_t)(brow + srow + 64) * K + k0 + schk);
    }
    __syncthreads();                   // prior reads done before overwrite
    if (SA == 0) {
      __builtin_amdgcn_global_load_lds(
          (const u32g*)(A + (size_t)(brow + srow) * K + k0 + schk),
          (u32l*)&lA[tid * 8], 16, 0, 0);
      __builtin_amdgcn_global_load_lds(
          (const u32g*)(A + (size_t)(brow + srow + 64) * K + k0 + schk),
          (u32l*)&lA[2048 + tid * 8], 16, 0, 0);
    } else {
      *(us8*)&lA[tid * 8]        = a0;
      *(us8*)&lA[2048 + tid * 8] = a1;
    }
    __builtin_amdgcn_global_load_lds(
        (const u32g*)(Bw + (size_t)(bcol + srow) * K + k0 + schk),
        (u32l*)&lB[tid * 8], 16, 0, 0);
    __builtin_amdgcn_global_load_lds(
        (const u32g*)(Bw + (size_t)(bcol + srow + 64) * K + k0 + schk),
        (u32l*)&lB[2048 + tid * 8], 16, 0, 0);
    __syncthreads();                   // drains DMA vmcnt + ds_writes
    bf8 af[4], bfv[4];
    #pragma unroll
    for (int mi = 0; mi < 4; ++mi)
      af[mi] = *(const bf8*)&lA[(wr + mi * 16 + fr) * 32 + fk];
    #pragma unroll
    for (int ni = 0; ni < 4; ++ni)
      bfv[ni] = *(const bf8*)&lB[(wc + ni * 16 + fr) * 32 + fk];
    #pragma unroll
    for (int mi = 0; mi < 4; ++mi)
      #pragma unroll
      for (int ni = 0; ni < 4; ++ni)
        acc[mi][ni] = __builtin_amdgcn_mfma_f32_16x16x32_bf16(af[mi], bfv[ni], acc[mi][ni], 0, 0, 0);
  }

  const int er = (lane >> 4) * 4;
  #pragma unroll
  for (int mi = 0; mi < 4; ++mi) {
    #pragma unroll
    for (int ni = 0; ni < 4; ++ni) {
      #pragma unroll
      for (int j = 0; j < 4; ++j) {
        const int r = brow + wr + mi * 16 + er + j;
        const int c = bcol + wc + ni * 16 + fr;
        float v = acc[mi][ni][j];
        if (MODE == 0) {
          v = (v + bias[c]) * scale;
          ((unsigned short*)Cout)[(size_t)r * DIM_ + c] = f2bf(v);
        } else if (MODE == 2) {
          ((float*)Cout)[(size_t)r * DIM_ + c] = v + bias[c];
        } else {                       // MODE 34
          v += frac[r] * bb[c];
          const int bb_ = r >> 8, key = r & 255;
          const int hh = c >> 6, dd = c & 63;
          const int bh = bb_ * NH_ + hh;
          size_t idx;
          if (isV) {
            idx = (size_t)bh * 16384 +
                ((key >> 5) * 4 + (dd >> 4)) * 512 + ((key >> 3) & 3) * 128 +
                (dd & 15) * 8 + (key & 7) + 786432;
          } else {
            const int t = key >> 5, g = (key >> 3) & 3, sub = (key >> 2) & 1, jj = key & 3;
            const int frk = g * 4 + jj;
            idx = (size_t)bh * 16384 +
                (((t * 2 + sub) * 2) + (dd >> 5)) * 512 + ((dd >> 3) & 3) * 128 +
                frk * 8 + (dd & 7);
          }
          ((unsigned short*)Cout)[idx] = f2bf(v);
        }
      }
    }
  }
}

// ---------------------------------------------------------------------------
// Fused low-rank attention — round-9 structure (1 q-tile/wave, no LDS, no
// barriers, all 16x16x32 MFMA) + TREE reductions for softmax max/sum
// (verified at the 2.44e-4 bf16 floor in round 11).
// ---------------------------------------------------------------------------
__global__ __launch_bounds__(256) void attn_fused(
    const unsigned short* __restrict__ Qh,   // [4,4096,768] bf16 (pre-scaled)
    const unsigned short* __restrict__ Kf,   // [48][16384] bf16 fragment-major
    const unsigned short* __restrict__ Vf,   // [48][16384] bf16 fragment-major
    unsigned short* __restrict__ ctx)        // [4,4096,768] bf16
{
  const int tid  = threadIdx.x;
  const int lane = tid & 63;
  const int wave = tid >> 6;
  const int bh = blockIdx.y;
  const int b = bh / NH_, h = bh % NH_;
  const int fr = lane & 15;
  const int hi = lane >> 4;
  const int qrow = blockIdx.x * 64 + wave * 16;

  const unsigned short* qp = Qh + (size_t)(b * SEQ_ + qrow + fr) * DIM_ + h * HD_ + hi * 8;
  const bf8 q0 = *(const bf8*)qp;
  const bf8 q1 = *(const bf8*)(qp + 32);

  // ---- QK^T: 8 key-groups of 32
  const unsigned short* kb = Kf + (size_t)bh * 16384 + lane * 8;
  f32x4 scA[8], scB[8];
  __builtin_amdgcn_s_setprio(1);
  #pragma unroll
  for (int s = 0; s < 8; ++s) {
    const bf8 ka0 = *(const bf8*)(kb + (s * 4 + 0) * 512);
    const bf8 ka1 = *(const bf8*)(kb + (s * 4 + 1) * 512);
    const bf8 kb0 = *(const bf8*)(kb + (s * 4 + 2) * 512);
    const bf8 kb1 = *(const bf8*)(kb + (s * 4 + 3) * 512);
    f32x4 x = (f32x4){0.f, 0.f, 0.f, 0.f};
    x = __builtin_amdgcn_mfma_f32_16x16x32_bf16(ka0, q0, x, 0, 0, 0);
    x = __builtin_amdgcn_mfma_f32_16x16x32_bf16(ka1, q1, x, 0, 0, 0);
    scA[s] = x;
    f32x4 y = (f32x4){0.f, 0.f, 0.f, 0.f};
    y = __builtin_amdgcn_mfma_f32_16x16x32_bf16(kb0, q0, y, 0, 0, 0);
    y = __builtin_amdgcn_mfma_f32_16x16x32_bf16(kb1, q1, y, 0, 0, 0);
    scB[s] = y;
  }
  __builtin_amdgcn_s_setprio(0);

  // ---- softmax max: f32x4-elementwise tree (depth 4) + horizontal + 2 shfl
  f32x4 tm[8];
  #pragma unroll
  for (int s = 0; s < 8; ++s) tm[s] = max4(scA[s], scB[s]);
  tm[0] = max4(tm[0], tm[4]); tm[1] = max4(tm[1], tm[5]);
  tm[2] = max4(tm[2], tm[6]); tm[3] = max4(tm[3], tm[7]);
  tm[0] = max4(tm[0], tm[2]); tm[1] = max4(tm[1], tm[3]);
  tm[0] = max4(tm[0], tm[1]);
  float m = fmaxf(fmaxf(tm[0][0], tm[0][1]), fmaxf(tm[0][2], tm[0][3]));
  m = fmaxf(m, __shfl_xor(m, 16));
  m = fmaxf(m, __shfl_xor(m, 32));

  // ---- exp2 + vector partial sums (two independent 8-chains)
  f32x4 uA = (f32x4){0.f, 0.f, 0.f, 0.f};
  f32x4 uB = (f32x4){0.f, 0.f, 0.f, 0.f};
  #pragma unroll
  for (int s = 0; s < 8; ++s) {
    #pragma unroll
    for (int j = 0; j < 4; ++j) {
      scA[s][j] = exp2f(scA[s][j] - m);
      scB[s][j] = exp2f(scB[s][j] - m);
    }
    uA += scA[s];
    uB += scB[s];
  }
  const f32x4 uv = uA + uB;
  float sum = (uv[0] + uv[1]) + (uv[2] + uv[3]);
  sum += __shfl_xor(sum, 16);
  sum += __shfl_xor(sum, 32);
  const float inv = 1.f / sum;

  // ---- pack normalized P (RNE) into K=32 A-fragments
  bf8 pa[8];
  #pragma unroll
  for (int s = 0; s < 8; ++s) {
    bf8 p;
    #pragma unroll
    for (int j = 0; j < 4; ++j) {
      p[j]     = (short)f2bf(scA[s][j] * inv);
      p[4 + j] = (short)f2bf(scB[s][j] * inv);
    }
    pa[s] = p;
  }

  // ---- PV: K=256 as 8 K=32 steps, 4 d-tiles
  const unsigned short* vb = Vf + (size_t)bh * 16384 + lane * 8;
  f32x4 acc[4];
  #pragma unroll
  for (int ct = 0; ct < 4; ++ct) acc[ct] = (f32x4){0.f, 0.f, 0.f, 0.f};
  __builtin_amdgcn_s_setprio(1);
  #pragma unroll
  for (int s = 0; s < 8; ++s) {
    #pragma unroll
    for (int ct = 0; ct < 4; ++ct) {
      const bf8 vf = *(const bf8*)(vb + (s * 4 + ct) * 512);
      acc[ct] = __builtin_amdgcn_mfma_f32_16x16x32_bf16(pa[s], vf, acc[ct], 0, 0, 0);
    }
  }
  __builtin_amdgcn_s_setprio(0);

  // ---- ctx write: lane holds O[q=qrow+hi*4+j][d=h*64+ct*16+fr]
  #pragma unroll
  for (int ct = 0; ct < 4; ++ct)
    #pragma unroll
    for (int j = 0; j < 4; ++j)
      ctx[(size_t)(b * SEQ_ + qrow + hi * 4 + j) * DIM_ + h * HD_ + ct * 16 + fr] =
          f2bf(acc[ct][j]);
}

// ---------------------------------------------------------------------------
extern "C" void kernel_launch(void* const* d_in, const int* in_sizes, int n_in,
                              void* d_out, int out_size, void* d_ws, size_t ws_size,
                              hipStream_t stream) {
  const float* query = (const float*)d_in[0];
  const float* key   = (const float*)d_in[1];
  const float* value = (const float*)d_in[2];
  const float* mask  = (const float*)d_in[3];
  const float* Wq    = (const float*)d_in[4];
  const float* bq    = (const float*)d_in[5];
  const float* Wk    = (const float*)d_in[6];
  const float* bk    = (const float*)d_in[7];
  const float* Wv    = (const float*)d_in[8];
  const float* bv    = (const float*)d_in[9];
  const float* Wo    = (const float*)d_in[10];
  const float* bo    = (const float*)d_in[11];
  float* out = (float*)d_out;

  char* ws = (char*)d_ws;
  unsigned short* Qh  = (unsigned short*)ws;                  // 25,165,824 B
  unsigned short* ctx = (unsigned short*)(ws + 25165824);     // 25,165,824 B
  unsigned short* pK  = (unsigned short*)(ws + 50331648);     //  1,572,864 B
  unsigned short* pV  = (unsigned short*)(ws + 51904512);     //  1,572,864 B (pK+786432 elems)
  unsigned short* Kf  = (unsigned short*)(ws + 53477376);     //  1,572,864 B
  unsigned short* Vf  = (unsigned short*)(ws + 55050240);     //  1,572,864 B (Kf+786432 elems)
  float*          frac = (float*)(ws + 56623104);             //      4,096 B
  unsigned short* Wbf = (unsigned short*)(ws + 56627200);     //  4,718,592 B

  const float qscale = 0.125f * LOG2E;   // 1/sqrt(64), e->2 exponent base

  pool_kernel<<<dim3(1024), dim3(384), 0, stream>>>(key, value, mask, pK, pV, frac);
  cvtbf_kernel<<<dim3(1152), dim3(256), 0, stream>>>(Wq, Wk, Wv, Wo, Wbf);
  gemm_bt<1, 0, 1><<<dim3(768), dim3(256), 0, stream>>>(
      query, Wbf, bq, nullptr, nullptr, Qh, qscale);
  gemm_bt<0, 34, 0><<<dim3(8, 6, 2), dim3(256), 0, stream>>>(
      pK, Wbf + DIM_*DIM_, bk, bv, frac, Kf, 1.f);
  attn_fused<<<dim3(64, 48), dim3(256), 0, stream>>>(Qh, Kf, Vf, ctx);
  gemm_bt<0, 2, 1><<<dim3(768), dim3(256), 0, stream>>>(
      ctx, Wbf + 3*DIM_*DIM_, bo, nullptr, nullptr, out, 1.f);
}

// Round 13
// 137.624 us; speedup vs baseline: 1.1050x; 1.0072x over previous
//
#include <hip/hip_runtime.h>

#define BS_   4
#define SEQ_  4096
#define DIM_  768
#define NH_   12
#define HD_   64
#define LK_   256

typedef __attribute__((ext_vector_type(8))) short          bf8;
typedef __attribute__((ext_vector_type(8))) unsigned short us8;
typedef __attribute__((ext_vector_type(4))) unsigned short us4;
typedef __attribute__((ext_vector_type(4))) float          f32x4;

typedef unsigned int u32g __attribute__((address_space(1)));
typedef unsigned int u32l __attribute__((address_space(3)));

#define LOG2E 1.44269504088896340736f

__device__ __forceinline__ unsigned short f2bf(float f) {
  unsigned u = __builtin_bit_cast(unsigned, f);
  u += 0x7fffu + ((u >> 16) & 1u);   // round-to-nearest-even
  return (unsigned short)(u >> 16);
}

__device__ __forceinline__ us8 cvt8(const float* __restrict__ p) {
  const float4 a = *(const float4*)p;
  const float4 b = *(const float4*)(p + 4);
  us8 r;
  r[0] = f2bf(a.x); r[1] = f2bf(a.y); r[2] = f2bf(a.z); r[3] = f2bf(a.w);
  r[4] = f2bf(b.x); r[5] = f2bf(b.y); r[6] = f2bf(b.z); r[7] = f2bf(b.w);
  return r;
}

__device__ __forceinline__ f32x4 max4(f32x4 a, f32x4 b) {
  f32x4 r;
  r[0] = fmaxf(a[0], b[0]); r[1] = fmaxf(a[1], b[1]);
  r[2] = fmaxf(a[2], b[2]); r[3] = fmaxf(a[3], b[3]);
  return r;
}

// ---------------------------------------------------------------------------
// bf16 pre-conversion of the four 768x768 weights (query stays f32; the
// Q-proj GEMM converts it in-register during A-staging).
// ---------------------------------------------------------------------------
__global__ __launch_bounds__(256) void cvtbf_kernel(
    const float* __restrict__ Wq, const float* __restrict__ Wk,
    const float* __restrict__ Wv, const float* __restrict__ Wo,
    unsigned short* __restrict__ Wbf)
{
  const int i = blockIdx.x * 256 + threadIdx.x;   // us8 index
  const int WN8 = (DIM_ * DIM_) / 8;              // 73728
  int j = i;
  const float* src; unsigned short* dst;
  if      (j <     WN8) { src = Wq; dst = Wbf;                   }
  else if (j < 2 * WN8) { src = Wk; dst = Wbf + DIM_*DIM_;     j -=     WN8; }
  else if (j < 3 * WN8) { src = Wv; dst = Wbf + 2*DIM_*DIM_;   j -= 2 * WN8; }
  else if (j < 4 * WN8) { src = Wo; dst = Wbf + 3*DIM_*DIM_;   j -= 3 * WN8; }
  else return;
  *(us8*)(dst + (size_t)j * 8) = cvt8(src + (size_t)j * 8);
}

// ---------------------------------------------------------------------------
// Pool (float4-vectorized): 384 threads; lanes 0-191 pool key, 192-383 value.
// ---------------------------------------------------------------------------
__global__ __launch_bounds__(384) void pool_kernel(
    const float* __restrict__ key, const float* __restrict__ value,
    const float* __restrict__ mask,
    unsigned short* __restrict__ pk, unsigned short* __restrict__ pv,
    float* __restrict__ frac)
{
  const int blk = blockIdx.x;          // 0..1023
  const int b = blk >> 8;
  const int l = blk & 255;
  const int tid = threadIdx.x;
  __shared__ float keep[16];
  if (tid < 16) keep[tid] = (mask[b * SEQ_ + l * 16 + tid] >= 0.f) ? 1.f : 0.f;
  __syncthreads();
  const int isV = tid >= 192;
  const int c = isV ? tid - 192 : tid;            // float4 chunk 0..191
  const float* src = isV ? value : key;
  float4 acc = make_float4(0.f, 0.f, 0.f, 0.f);
  #pragma unroll 1
  for (int w = 0; w < 16; ++w) {
    if (keep[w] != 0.f) {
      const float4 v = *(const float4*)(src + (size_t)(b * SEQ_ + l * 16 + w) * DIM_ + c * 4);
      acc.x += v.x; acc.y += v.y; acc.z += v.z; acc.w += v.w;
    }
  }
  const float s = 1.f / 16.f;
  unsigned short* dst = isV ? pv : pk;
  us4 o4;
  o4[0] = f2bf(acc.x * s); o4[1] = f2bf(acc.y * s);
  o4[2] = f2bf(acc.z * s); o4[3] = f2bf(acc.w * s);
  *(us4*)(dst + (size_t)(b * LK_ + l) * DIM_ + c * 4) = o4;
  if (tid == 0) {
    float cnt = 0.f;
    for (int w = 0; w < 16; ++w) cnt += keep[w];
    frac[b * LK_ + l] = cnt * s;
  }
}

// ---------------------------------------------------------------------------
// C = A @ B^T (+ epilogue).  128x128 tile, BK=32, 4 waves, 16x16x32 bf16 MFMA.
// TEMPLATE-specialized staging (round-11 lesson: a runtime branch here
// defeats the compiler's load pipelining — 2.7x slowdown).
// SA=0: A bf16 via global_load_lds; SA=1: A f32, cvt8 in-register + ds_write.
// SWZ: 1D grid of 768, XCD-chunked swizzle.
// MODE 0: out_bf16 = (acc + bias[c]) * scale               (Q projection)
// MODE 2: out_f32  = acc + bias[c]                         (output projection)
// MODE 34: fused K/V projection pair, blockIdx.z selects:
//   z=0 (K): acc + frac[r]*bias[c] -> Kf, key-rows permuted so the two
//            swapped-QK^T sub-tiles concatenate into the K=32 PV A-fragment.
//   z=1 (V): acc + frac[r]*bias2[c] -> Vf, K=32 B-frag order (+786432 elems).
// ---------------------------------------------------------------------------
template<int SA, int MODE, int SWZ>
__global__ __launch_bounds__(256) void gemm_bt(
    const void* __restrict__ Aptr_, const void* __restrict__ Bptr_,
    const float* __restrict__ bias, const float* __restrict__ bias2,
    const float* __restrict__ frac,
    void* __restrict__ Cout, float scale)
{
  constexpr int K = DIM_;
  __shared__ __align__(16) unsigned short lA[128 * 32];
  __shared__ __align__(16) unsigned short lB[128 * 32];
  const int tid  = threadIdx.x;
  const int lane = tid & 63;
  const int wave = tid >> 6;

  int bx, by;
  if (SWZ) {
    const int r = (blockIdx.x & 7) * 96 + (blockIdx.x >> 3);
    bx = r / 6; by = r % 6;
  } else {
    bx = blockIdx.x; by = blockIdx.y;
  }
  const int brow = bx * 128;
  const int bcol = by * 128;

  const unsigned short* A = (const unsigned short*)Aptr_;   // SA=0
  const float*          Af = (const float*)Aptr_;           // SA=1
  const unsigned short* Bw = (const unsigned short*)Bptr_;
  const float* bb = bias;
  int isV = 0;
  if (MODE == 34) {
    isV = blockIdx.z;
    A  += (size_t)isV * (BS_ * LK_ * DIM_);    // pV follows pK
    Bw += (size_t)isV * (DIM_ * DIM_);         // Wv follows Wk
    if (isV) bb = bias2;
  }

  const int wr   = (wave >> 1) * 64;
  const int wc   = (wave & 1) * 64;
  const int fr   = lane & 15;
  const int fk   = (lane >> 4) * 8;

  f32x4 acc[4][4];
  #pragma unroll
  for (int i = 0; i < 4; ++i)
    #pragma unroll
    for (int j = 0; j < 4; ++j) acc[i][j] = (f32x4){0.f, 0.f, 0.f, 0.f};

  const int srow = tid >> 2;           // 0..63
  const int schk = (tid & 3) * 8;      // k element offset

  for (int k0 = 0; k0 < K; k0 += 32) {
    us8 a0, a1;
    if (SA == 1) {
      a0 = cvt8(Af + (size_t)(brow + srow) * K + k0 + schk);
      a1 = cvt8(Af + (size_t)(brow + srow + 64) * K + k0 + schk);
    }
    __syncthreads();                   // prior reads done before overwrite
    if (SA == 0) {
      __builtin_amdgcn_global_load_lds(
          (const u32g*)(A + (size_t)(brow + srow) * K + k0 + schk),
          (u32l*)&lA[tid * 8], 16, 0, 0);
      __builtin_amdgcn_global_load_lds(
          (const u32g*)(A + (size_t)(brow + srow + 64) * K + k0 + schk),
          (u32l*)&lA[2048 + tid * 8], 16, 0, 0);
    } else {
      *(us8*)&lA[tid * 8]        = a0;
      *(us8*)&lA[2048 + tid * 8] = a1;
    }
    __builtin_amdgcn_global_load_lds(
        (const u32g*)(Bw + (size_t)(bcol + srow) * K + k0 + schk),
        (u32l*)&lB[tid * 8], 16, 0, 0);
    __builtin_amdgcn_global_load_lds(
        (const u32g*)(Bw + (size_t)(bcol + srow + 64) * K + k0 + schk),
        (u32l*)&lB[2048 + tid * 8], 16, 0, 0);
    __syncthreads();                   // drains DMA vmcnt + ds_writes
    bf8 af[4], bfv[4];
    #pragma unroll
    for (int mi = 0; mi < 4; ++mi)
      af[mi] = *(const bf8*)&lA[(wr + mi * 16 + fr) * 32 + fk];
    #pragma unroll
    for (int ni = 0; ni < 4; ++ni)
      bfv[ni] = *(const bf8*)&lB[(wc + ni * 16 + fr) * 32 + fk];
    #pragma unroll
    for (int mi = 0; mi < 4; ++mi)
      #pragma unroll
      for (int ni = 0; ni < 4; ++ni)
        acc[mi][ni] = __builtin_amdgcn_mfma_f32_16x16x32_bf16(af[mi], bfv[ni], acc[mi][ni], 0, 0, 0);
  }

  const int er = (lane >> 4) * 4;
  #pragma unroll
  for (int mi = 0; mi < 4; ++mi) {
    #pragma unroll
    for (int ni = 0; ni < 4; ++ni) {
      #pragma unroll
      for (int j = 0; j < 4; ++j) {
        const int r = brow + wr + mi * 16 + er + j;
        const int c = bcol + wc + ni * 16 + fr;
        float v = acc[mi][ni][j];
        if (MODE == 0) {
          v = (v + bias[c]) * scale;
          ((unsigned short*)Cout)[(size_t)r * DIM_ + c] = f2bf(v);
        } else if (MODE == 2) {
          ((float*)Cout)[(size_t)r * DIM_ + c] = v + bias[c];
        } else {                       // MODE 34
          v += frac[r] * bb[c];
          const int bb_ = r >> 8, key = r & 255;
          const int hh = c >> 6, dd = c & 63;
          const int bh = bb_ * NH_ + hh;
          size_t idx;
          if (isV) {
            idx = (size_t)bh * 16384 +
                ((key >> 5) * 4 + (dd >> 4)) * 512 + ((key >> 3) & 3) * 128 +
                (dd & 15) * 8 + (key & 7) + 786432;
          } else {
            const int t = key >> 5, g = (key >> 3) & 3, sub = (key >> 2) & 1, jj = key & 3;
            const int frk = g * 4 + jj;
            idx = (size_t)bh * 16384 +
                (((t * 2 + sub) * 2) + (dd >> 5)) * 512 + ((dd >> 3) & 3) * 128 +
                frk * 8 + (dd & 7);
          }
          ((unsigned short*)Cout)[idx] = f2bf(v);
        }
      }
    }
  }
}

// ---------------------------------------------------------------------------
// Fused low-rank attention — 1024-thread blocks, LDS-staged K/V head.
// Block = one (b,h) x 256 q-rows (16 waves x 16 rows); grid 16 x 48 = 768
// blocks = exactly 3 CU-rounds.  K+V (64 KB) staged ONCE per block via
// global_load_lds (both sides lane-linear), ONE barrier, then each wave
// runs the round-12 register pipeline unchanged with chunk reads from LDS
// (chunk*512 + lane*8 -> 64x16B contiguous, conflict-free).  Cuts K/V L2
// traffic 16x (786 MB -> 49 MB) and doubles resident waves/CU.
// Softmax = round-11-verified tree reductions (2^-12 floor).
// ---------------------------------------------------------------------------
__global__ __launch_bounds__(1024, 4) void attn_fused(
    const unsigned short* __restrict__ Qh,   // [4,4096,768] bf16 (pre-scaled)
    const unsigned short* __restrict__ Kf,   // [48][16384] bf16 fragment-major
    const unsigned short* __restrict__ Vf,   // [48][16384] bf16 fragment-major
    unsigned short* __restrict__ ctx)        // [4,4096,768] bf16
{
  __shared__ __align__(16) unsigned short Ks[16384];   // 32 KB
  __shared__ __align__(16) unsigned short Vs[16384];   // 32 KB
  const int tid  = threadIdx.x;          // 0..1023
  const int lane = tid & 63;
  const int wave = tid >> 6;             // 0..15
  const int bh = blockIdx.y;
  const int b = bh / NH_, h = bh % NH_;
  const int fr = lane & 15;
  const int hi = lane >> 4;
  const int qrow = blockIdx.x * 256 + wave * 16;

  // ---- stage K/V head (64 KB) once: linear global -> linear LDS
  {
    const unsigned short* kg = Kf + (size_t)bh * 16384 + tid * 8;
    const unsigned short* vg = Vf + (size_t)bh * 16384 + tid * 8;
    __builtin_amdgcn_global_load_lds((const u32g*)kg,          (u32l*)&Ks[tid * 8],        16, 0, 0);
    __builtin_amdgcn_global_load_lds((const u32g*)(kg + 8192), (u32l*)&Ks[8192 + tid * 8], 16, 0, 0);
    __builtin_amdgcn_global_load_lds((const u32g*)vg,          (u32l*)&Vs[tid * 8],        16, 0, 0);
    __builtin_amdgcn_global_load_lds((const u32g*)(vg + 8192), (u32l*)&Vs[8192 + tid * 8], 16, 0, 0);
  }

  // ---- Q fragments (global; issued before the barrier drain)
  const unsigned short* qp = Qh + (size_t)(b * SEQ_ + qrow + fr) * DIM_ + h * HD_ + hi * 8;
  const bf8 q0 = *(const bf8*)qp;
  const bf8 q1 = *(const bf8*)(qp + 32);

  __syncthreads();   // drains DMA vmcnt; Ks/Vs visible block-wide

  // ---- QK^T: 8 key-groups of 32
  f32x4 scA[8], scB[8];
  __builtin_amdgcn_s_setprio(1);
  #pragma unroll
  for (int s = 0; s < 8; ++s) {
    const bf8 ka0 = *(const bf8*)&Ks[(s * 4 + 0) * 512 + lane * 8];
    const bf8 ka1 = *(const bf8*)&Ks[(s * 4 + 1) * 512 + lane * 8];
    const bf8 kb0 = *(const bf8*)&Ks[(s * 4 + 2) * 512 + lane * 8];
    const bf8 kb1 = *(const bf8*)&Ks[(s * 4 + 3) * 512 + lane * 8];
    f32x4 x = (f32x4){0.f, 0.f, 0.f, 0.f};
    x = __builtin_amdgcn_mfma_f32_16x16x32_bf16(ka0, q0, x, 0, 0, 0);
    x = __builtin_amdgcn_mfma_f32_16x16x32_bf16(ka1, q1, x, 0, 0, 0);
    scA[s] = x;
    f32x4 y = (f32x4){0.f, 0.f, 0.f, 0.f};
    y = __builtin_amdgcn_mfma_f32_16x16x32_bf16(kb0, q0, y, 0, 0, 0);
    y = __builtin_amdgcn_mfma_f32_16x16x32_bf16(kb1, q1, y, 0, 0, 0);
    scB[s] = y;
  }
  __builtin_amdgcn_s_setprio(0);

  // ---- softmax max: f32x4-elementwise tree + horizontal + 2 shfl
  f32x4 tm[8];
  #pragma unroll
  for (int s = 0; s < 8; ++s) tm[s] = max4(scA[s], scB[s]);
  tm[0] = max4(tm[0], tm[4]); tm[1] = max4(tm[1], tm[5]);
  tm[2] = max4(tm[2], tm[6]); tm[3] = max4(tm[3], tm[7]);
  tm[0] = max4(tm[0], tm[2]); tm[1] = max4(tm[1], tm[3]);
  tm[0] = max4(tm[0], tm[1]);
  float m = fmaxf(fmaxf(tm[0][0], tm[0][1]), fmaxf(tm[0][2], tm[0][3]));
  m = fmaxf(m, __shfl_xor(m, 16));
  m = fmaxf(m, __shfl_xor(m, 32));

  // ---- exp2 + vector partial sums (two independent 8-chains)
  f32x4 uA = (f32x4){0.f, 0.f, 0.f, 0.f};
  f32x4 uB = (f32x4){0.f, 0.f, 0.f, 0.f};
  #pragma unroll
  for (int s = 0; s < 8; ++s) {
    #pragma unroll
    for (int j = 0; j < 4; ++j) {
      scA[s][j] = exp2f(scA[s][j] - m);
      scB[s][j] = exp2f(scB[s][j] - m);
    }
    uA += scA[s];
    uB += scB[s];
  }
  const f32x4 uv = uA + uB;
  float sum = (uv[0] + uv[1]) + (uv[2] + uv[3]);
  sum += __shfl_xor(sum, 16);
  sum += __shfl_xor(sum, 32);
  const float inv = 1.f / sum;

  // ---- pack normalized P (RNE) into K=32 A-fragments
  bf8 pa[8];
  #pragma unroll
  for (int s = 0; s < 8; ++s) {
    bf8 p;
    #pragma unroll
    for (int j = 0; j < 4; ++j) {
      p[j]     = (short)f2bf(scA[s][j] * inv);
      p[4 + j] = (short)f2bf(scB[s][j] * inv);
    }
    pa[s] = p;
  }

  // ---- PV: K=256 as 8 K=32 steps, 4 d-tiles
  f32x4 acc[4];
  #pragma unroll
  for (int ct = 0; ct < 4; ++ct) acc[ct] = (f32x4){0.f, 0.f, 0.f, 0.f};
  __builtin_amdgcn_s_setprio(1);
  #pragma unroll
  for (int s = 0; s < 8; ++s) {
    #pragma unroll
    for (int ct = 0; ct < 4; ++ct) {
      const bf8 vf = *(const bf8*)&Vs[(s * 4 + ct) * 512 + lane * 8];
      acc[ct] = __builtin_amdgcn_mfma_f32_16x16x32_bf16(pa[s], vf, acc[ct], 0, 0, 0);
    }
  }
  __builtin_amdgcn_s_setprio(0);

  // ---- ctx write: lane holds O[q=qrow+hi*4+j][d=h*64+ct*16+fr]
  #pragma unroll
  for (int ct = 0; ct < 4; ++ct)
    #pragma unroll
    for (int j = 0; j < 4; ++j)
      ctx[(size_t)(b * SEQ_ + qrow + hi * 4 + j) * DIM_ + h * HD_ + ct * 16 + fr] =
          f2bf(acc[ct][j]);
}

// ---------------------------------------------------------------------------
extern "C" void kernel_launch(void* const* d_in, const int* in_sizes, int n_in,
                              void* d_out, int out_size, void* d_ws, size_t ws_size,
                              hipStream_t stream) {
  const float* query = (const float*)d_in[0];
  const float* key   = (const float*)d_in[1];
  const float* value = (const float*)d_in[2];
  const float* mask  = (const float*)d_in[3];
  const float* Wq    = (const float*)d_in[4];
  const float* bq    = (const float*)d_in[5];
  const float* Wk    = (const float*)d_in[6];
  const float* bk    = (const float*)d_in[7];
  const float* Wv    = (const float*)d_in[8];
  const float* bv    = (const float*)d_in[9];
  const float* Wo    = (const float*)d_in[10];
  const float* bo    = (const float*)d_in[11];
  float* out = (float*)d_out;

  char* ws = (char*)d_ws;
  unsigned short* Qh  = (unsigned short*)ws;                  // 25,165,824 B
  unsigned short* ctx = (unsigned short*)(ws + 25165824);     // 25,165,824 B
  unsigned short* pK  = (unsigned short*)(ws + 50331648);     //  1,572,864 B
  unsigned short* pV  = (unsigned short*)(ws + 51904512);     //  1,572,864 B (pK+786432 elems)
  unsigned short* Kf  = (unsigned short*)(ws + 53477376);     //  1,572,864 B
  unsigned short* Vf  = (unsigned short*)(ws + 55050240);     //  1,572,864 B (Kf+786432 elems)
  float*          frac = (float*)(ws + 56623104);             //      4,096 B
  unsigned short* Wbf = (unsigned short*)(ws + 56627200);     //  4,718,592 B

  const float qscale = 0.125f * LOG2E;   // 1/sqrt(64), e->2 exponent base

  pool_kernel<<<dim3(1024), dim3(384), 0, stream>>>(key, value, mask, pK, pV, frac);
  cvtbf_kernel<<<dim3(1152), dim3(256), 0, stream>>>(Wq, Wk, Wv, Wo, Wbf);
  gemm_bt<1, 0, 1><<<dim3(768), dim3(256), 0, stream>>>(
      query, Wbf, bq, nullptr, nullptr, Qh, qscale);
  gemm_bt<0, 34, 0><<<dim3(8, 6, 2), dim3(256), 0, stream>>>(
      pK, Wbf + DIM_*DIM_, bk, bv, frac, Kf, 1.f);
  attn_fused<<<dim3(16, 48), dim3(1024), 0, stream>>>(Qh, Kf, Vf, ctx);
  gemm_bt<0, 2, 1><<<dim3(768), dim3(256), 0, stream>>>(
      ctx, Wbf + 3*DIM_*DIM_, bo, nullptr, nullptr, out, 1.f);
}

// Round 14
// 137.340 us; speedup vs baseline: 1.1072x; 1.0021x over previous
//
#include <hip/hip_runtime.h>

#define BS_   4
#define SEQ_  4096
#define DIM_  768
#define NH_   12
#define HD_   64
#define LK_   256

typedef __attribute__((ext_vector_type(8))) short          bf8;
typedef __attribute__((ext_vector_type(8))) unsigned short us8;
typedef __attribute__((ext_vector_type(4))) unsigned short us4;
typedef __attribute__((ext_vector_type(4))) float          f32x4;

typedef unsigned int u32g __attribute__((address_space(1)));
typedef unsigned int u32l __attribute__((address_space(3)));

#define LOG2E 1.44269504088896340736f

__device__ __forceinline__ unsigned short f2bf(float f) {
  unsigned u = __builtin_bit_cast(unsigned, f);
  u += 0x7fffu + ((u >> 16) & 1u);   // round-to-nearest-even
  return (unsigned short)(u >> 16);
}

__device__ __forceinline__ us8 cvt8(const float* __restrict__ p) {
  const float4 a = *(const float4*)p;
  const float4 b = *(const float4*)(p + 4);
  us8 r;
  r[0] = f2bf(a.x); r[1] = f2bf(a.y); r[2] = f2bf(a.z); r[3] = f2bf(a.w);
  r[4] = f2bf(b.x); r[5] = f2bf(b.y); r[6] = f2bf(b.z); r[7] = f2bf(b.w);
  return r;
}

__device__ __forceinline__ f32x4 max4(f32x4 a, f32x4 b) {
  f32x4 r;
  r[0] = fmaxf(a[0], b[0]); r[1] = fmaxf(a[1], b[1]);
  r[2] = fmaxf(a[2], b[2]); r[3] = fmaxf(a[3], b[3]);
  return r;
}

// ---------------------------------------------------------------------------
// bf16 pre-conversion of the four 768x768 weights (query stays f32; the
// Q-proj GEMM converts it in-register during A-staging).
// ---------------------------------------------------------------------------
__global__ __launch_bounds__(256) void cvtbf_kernel(
    const float* __restrict__ Wq, const float* __restrict__ Wk,
    const float* __restrict__ Wv, const float* __restrict__ Wo,
    unsigned short* __restrict__ Wbf)
{
  const int i = blockIdx.x * 256 + threadIdx.x;   // us8 index
  const int WN8 = (DIM_ * DIM_) / 8;              // 73728
  int j = i;
  const float* src; unsigned short* dst;
  if      (j <     WN8) { src = Wq; dst = Wbf;                   }
  else if (j < 2 * WN8) { src = Wk; dst = Wbf + DIM_*DIM_;     j -=     WN8; }
  else if (j < 3 * WN8) { src = Wv; dst = Wbf + 2*DIM_*DIM_;   j -= 2 * WN8; }
  else if (j < 4 * WN8) { src = Wo; dst = Wbf + 3*DIM_*DIM_;   j -= 3 * WN8; }
  else return;
  *(us8*)(dst + (size_t)j * 8) = cvt8(src + (size_t)j * 8);
}

// ---------------------------------------------------------------------------
// Pool (float4-vectorized): 384 threads; lanes 0-191 pool key, 192-383 value.
// ---------------------------------------------------------------------------
__global__ __launch_bounds__(384) void pool_kernel(
    const float* __restrict__ key, const float* __restrict__ value,
    const float* __restrict__ mask,
    unsigned short* __restrict__ pk, unsigned short* __restrict__ pv,
    float* __restrict__ frac)
{
  const int blk = blockIdx.x;          // 0..1023
  const int b = blk >> 8;
  const int l = blk & 255;
  const int tid = threadIdx.x;
  __shared__ float keep[16];
  if (tid < 16) keep[tid] = (mask[b * SEQ_ + l * 16 + tid] >= 0.f) ? 1.f : 0.f;
  __syncthreads();
  const int isV = tid >= 192;
  const int c = isV ? tid - 192 : tid;            // float4 chunk 0..191
  const float* src = isV ? value : key;
  float4 acc = make_float4(0.f, 0.f, 0.f, 0.f);
  #pragma unroll 1
  for (int w = 0; w < 16; ++w) {
    if (keep[w] != 0.f) {
      const float4 v = *(const float4*)(src + (size_t)(b * SEQ_ + l * 16 + w) * DIM_ + c * 4);
      acc.x += v.x; acc.y += v.y; acc.z += v.z; acc.w += v.w;
    }
  }
  const float s = 1.f / 16.f;
  unsigned short* dst = isV ? pv : pk;
  us4 o4;
  o4[0] = f2bf(acc.x * s); o4[1] = f2bf(acc.y * s);
  o4[2] = f2bf(acc.z * s); o4[3] = f2bf(acc.w * s);
  *(us4*)(dst + (size_t)(b * LK_ + l) * DIM_ + c * 4) = o4;
  if (tid == 0) {
    float cnt = 0.f;
    for (int w = 0; w < 16; ++w) cnt += keep[w];
    frac[b * LK_ + l] = cnt * s;
  }
}

// ---------------------------------------------------------------------------
// C = A @ B^T (+ epilogue).  128x128 tile, BK=32, 4 waves, 16x16x32 bf16 MFMA.
// Round-14 GEMM core:
//  * double-buffered LDS prefetch (stage t+1 before compute t; ONE
//    vmcnt+barrier per tile instead of two barriers + cold stall);
//  * T14 ordering for the SA=1 f32 path (loads at loop top, ds_write after
//    compute) so the query-conversion latency hides under MFMA;
//  * XOR chunk-swizzle: global SOURCE chunk = (tid&3) ^ ((srow>>1)&3), LDS
//    dest linear (the legal global_load_lds pattern); fragment reads apply
//    the same XOR -> bank-quad = 4*(r&1) + (c^g(r)) covers all 8 quads
//    exactly 2x per 16-lane group = conflict-free (was 8-way).
// MODE 0: out_bf16 = (acc + bias[c]) * scale               (Q projection)
// MODE 2: out_f32  = acc + bias[c]                         (output projection)
// MODE 34: fused K/V projection pair, blockIdx.z selects Kf/Vf layouts.
// ---------------------------------------------------------------------------
template<int SA, int MODE, int SWZ>
__global__ __launch_bounds__(256) void gemm_bt(
    const void* __restrict__ Aptr_, const void* __restrict__ Bptr_,
    const float* __restrict__ bias, const float* __restrict__ bias2,
    const float* __restrict__ frac,
    void* __restrict__ Cout, float scale)
{
  constexpr int K = DIM_;
  constexpr int NT = K / 32;           // 24 K-tiles
  __shared__ __align__(16) unsigned short lA[2][4096];
  __shared__ __align__(16) unsigned short lB[2][4096];
  const int tid  = threadIdx.x;
  const int lane = tid & 63;
  const int wave = tid >> 6;

  int bx, by;
  if (SWZ) {
    const int r = (blockIdx.x & 7) * 96 + (blockIdx.x >> 3);
    bx = r / 6; by = r % 6;
  } else {
    bx = blockIdx.x; by = blockIdx.y;
  }
  const int brow = bx * 128;
  const int bcol = by * 128;

  const unsigned short* A = (const unsigned short*)Aptr_;   // SA=0
  const float*          Af = (const float*)Aptr_;           // SA=1
  const unsigned short* Bw = (const unsigned short*)Bptr_;
  const float* bb = bias;
  int isV = 0;
  if (MODE == 34) {
    isV = blockIdx.z;
    A  += (size_t)isV * (BS_ * LK_ * DIM_);    // pV follows pK
    Bw += (size_t)isV * (DIM_ * DIM_);         // Wv follows Wk
    if (isV) bb = bias2;
  }

  const int wr   = (wave >> 1) * 64;
  const int wc   = (wave & 1) * 64;
  const int fr   = lane & 15;
  const int rg   = (fr >> 1) & 3;      // read-side swizzle
  const int cph  = ((lane >> 4) ^ rg) * 8;   // physical chunk offset for reads

  f32x4 acc[4][4];
  #pragma unroll
  for (int i = 0; i < 4; ++i)
    #pragma unroll
    for (int j = 0; j < 4; ++j) acc[i][j] = (f32x4){0.f, 0.f, 0.f, 0.f};

  const int srow = tid >> 2;                       // 0..63
  const int schk = (((tid & 3) ^ ((srow >> 1) & 3))) * 8;  // swizzled src chunk

  auto STAGE = [&](int k0, int b) {   // DMA paths (B always; A when SA==0)
    if (SA == 0) {
      __builtin_amdgcn_global_load_lds(
          (const u32g*)(A + (size_t)(brow + srow) * K + k0 + schk),
          (u32l*)&lA[b][tid * 8], 16, 0, 0);
      __builtin_amdgcn_global_load_lds(
          (const u32g*)(A + (size_t)(brow + srow + 64) * K + k0 + schk),
          (u32l*)&lA[b][2048 + tid * 8], 16, 0, 0);
    }
    __builtin_amdgcn_global_load_lds(
        (const u32g*)(Bw + (size_t)(bcol + srow) * K + k0 + schk),
        (u32l*)&lB[b][tid * 8], 16, 0, 0);
    __builtin_amdgcn_global_load_lds(
        (const u32g*)(Bw + (size_t)(bcol + srow + 64) * K + k0 + schk),
        (u32l*)&lB[b][2048 + tid * 8], 16, 0, 0);
  };

  auto COMPUTE = [&](int b) {
    bf8 af[4], bfv[4];
    #pragma unroll
    for (int mi = 0; mi < 4; ++mi)
      af[mi] = *(const bf8*)&lA[b][(wr + mi * 16 + fr) * 32 + cph];
    #pragma unroll
    for (int ni = 0; ni < 4; ++ni)
      bfv[ni] = *(const bf8*)&lB[b][(wc + ni * 16 + fr) * 32 + cph];
    #pragma unroll
    for (int mi = 0; mi < 4; ++mi)
      #pragma unroll
      for (int ni = 0; ni < 4; ++ni)
        acc[mi][ni] = __builtin_amdgcn_mfma_f32_16x16x32_bf16(af[mi], bfv[ni], acc[mi][ni], 0, 0, 0);
  };

  // ---- prologue: stage tile 0 into buf 0
  if (SA == 1) {
    const us8 a0 = cvt8(Af + (size_t)(brow + srow) * K + schk);
    const us8 a1 = cvt8(Af + (size_t)(brow + srow + 64) * K + schk);
    *(us8*)&lA[0][tid * 8]        = a0;
    *(us8*)&lA[0][2048 + tid * 8] = a1;
  }
  STAGE(0, 0);
  __syncthreads();

  int buf = 0;
  #pragma unroll 2
  for (int t = 0; t < NT - 1; ++t) {
    const int k1 = (t + 1) * 32;
    us8 a0, a1;
    if (SA == 1) {          // issue next-tile loads EARLY (T14)
      a0 = cvt8(Af + (size_t)(brow + srow) * K + k1 + schk);
      a1 = cvt8(Af + (size_t)(brow + srow + 64) * K + k1 + schk);
    }
    STAGE(k1, buf ^ 1);     // fire-and-forget DMA into the other buffer
    COMPUTE(buf);           // hide load latency under ds_read + MFMA
    if (SA == 1) {          // write-late into the other buffer
      *(us8*)&lA[buf ^ 1][tid * 8]        = a0;
      *(us8*)&lA[buf ^ 1][2048 + tid * 8] = a1;
    }
    __syncthreads();        // one drain per tile
    buf ^= 1;
  }
  COMPUTE(buf);

  const int er = (lane >> 4) * 4;
  #pragma unroll
  for (int mi = 0; mi < 4; ++mi) {
    #pragma unroll
    for (int ni = 0; ni < 4; ++ni) {
      #pragma unroll
      for (int j = 0; j < 4; ++j) {
        const int r = brow + wr + mi * 16 + er + j;
        const int c = bcol + wc + ni * 16 + fr;
        float v = acc[mi][ni][j];
        if (MODE == 0) {
          v = (v + bias[c]) * scale;
          ((unsigned short*)Cout)[(size_t)r * DIM_ + c] = f2bf(v);
        } else if (MODE == 2) {
          ((float*)Cout)[(size_t)r * DIM_ + c] = v + bias[c];
        } else {                       // MODE 34
          v += frac[r] * bb[c];
          const int bb_ = r >> 8, key = r & 255;
          const int hh = c >> 6, dd = c & 63;
          const int bh = bb_ * NH_ + hh;
          size_t idx;
          if (isV) {
            idx = (size_t)bh * 16384 +
                ((key >> 5) * 4 + (dd >> 4)) * 512 + ((key >> 3) & 3) * 128 +
                (dd & 15) * 8 + (key & 7) + 786432;
          } else {
            const int t = key >> 5, g = (key >> 3) & 3, sub = (key >> 2) & 1, jj = key & 3;
            const int frk = g * 4 + jj;
            idx = (size_t)bh * 16384 +
                (((t * 2 + sub) * 2) + (dd >> 5)) * 512 + ((dd >> 3) & 3) * 128 +
                frk * 8 + (dd & 7);
          }
          ((unsigned short*)Cout)[idx] = f2bf(v);
        }
      }
    }
  }
}

// ---------------------------------------------------------------------------
// Fused low-rank attention — 1024-thread blocks, LDS-staged K/V head.
// (unchanged from round 13: K+V staged once via global_load_lds, one
// barrier, register pipeline, tree-reduction softmax at the 2^-12 floor)
// ---------------------------------------------------------------------------
__global__ __launch_bounds__(1024, 4) void attn_fused(
    const unsigned short* __restrict__ Qh,   // [4,4096,768] bf16 (pre-scaled)
    const unsigned short* __restrict__ Kf,   // [48][16384] bf16 fragment-major
    const unsigned short* __restrict__ Vf,   // [48][16384] bf16 fragment-major
    unsigned short* __restrict__ ctx)        // [4,4096,768] bf16
{
  __shared__ __align__(16) unsigned short Ks[16384];   // 32 KB
  __shared__ __align__(16) unsigned short Vs[16384];   // 32 KB
  const int tid  = threadIdx.x;          // 0..1023
  const int lane = tid & 63;
  const int wave = tid >> 6;             // 0..15
  const int bh = blockIdx.y;
  const int b = bh / NH_, h = bh % NH_;
  const int fr = lane & 15;
  const int hi = lane >> 4;
  const int qrow = blockIdx.x * 256 + wave * 16;

  // ---- stage K/V head (64 KB) once: linear global -> linear LDS
  {
    const unsigned short* kg = Kf + (size_t)bh * 16384 + tid * 8;
    const unsigned short* vg = Vf + (size_t)bh * 16384 + tid * 8;
    __builtin_amdgcn_global_load_lds((const u32g*)kg,          (u32l*)&Ks[tid * 8],        16, 0, 0);
    __builtin_amdgcn_global_load_lds((const u32g*)(kg + 8192), (u32l*)&Ks[8192 + tid * 8], 16, 0, 0);
    __builtin_amdgcn_global_load_lds((const u32g*)vg,          (u32l*)&Vs[tid * 8],        16, 0, 0);
    __builtin_amdgcn_global_load_lds((const u32g*)(vg + 8192), (u32l*)&Vs[8192 + tid * 8], 16, 0, 0);
  }

  // ---- Q fragments (global; issued before the barrier drain)
  const unsigned short* qp = Qh + (size_t)(b * SEQ_ + qrow + fr) * DIM_ + h * HD_ + hi * 8;
  const bf8 q0 = *(const bf8*)qp;
  const bf8 q1 = *(const bf8*)(qp + 32);

  __syncthreads();   // drains DMA vmcnt; Ks/Vs visible block-wide

  // ---- QK^T: 8 key-groups of 32
  f32x4 scA[8], scB[8];
  __builtin_amdgcn_s_setprio(1);
  #pragma unroll
  for (int s = 0; s < 8; ++s) {
    const bf8 ka0 = *(const bf8*)&Ks[(s * 4 + 0) * 512 + lane * 8];
    const bf8 ka1 = *(const bf8*)&Ks[(s * 4 + 1) * 512 + lane * 8];
    const bf8 kb0 = *(const bf8*)&Ks[(s * 4 + 2) * 512 + lane * 8];
    const bf8 kb1 = *(const bf8*)&Ks[(s * 4 + 3) * 512 + lane * 8];
    f32x4 x = (f32x4){0.f, 0.f, 0.f, 0.f};
    x = __builtin_amdgcn_mfma_f32_16x16x32_bf16(ka0, q0, x, 0, 0, 0);
    x = __builtin_amdgcn_mfma_f32_16x16x32_bf16(ka1, q1, x, 0, 0, 0);
    scA[s] = x;
    f32x4 y = (f32x4){0.f, 0.f, 0.f, 0.f};
    y = __builtin_amdgcn_mfma_f32_16x16x32_bf16(kb0, q0, y, 0, 0, 0);
    y = __builtin_amdgcn_mfma_f32_16x16x32_bf16(kb1, q1, y, 0, 0, 0);
    scB[s] = y;
  }
  __builtin_amdgcn_s_setprio(0);

  // ---- softmax max: f32x4-elementwise tree + horizontal + 2 shfl
  f32x4 tm[8];
  #pragma unroll
  for (int s = 0; s < 8; ++s) tm[s] = max4(scA[s], scB[s]);
  tm[0] = max4(tm[0], tm[4]); tm[1] = max4(tm[1], tm[5]);
  tm[2] = max4(tm[2], tm[6]); tm[3] = max4(tm[3], tm[7]);
  tm[0] = max4(tm[0], tm[2]); tm[1] = max4(tm[1], tm[3]);
  tm[0] = max4(tm[0], tm[1]);
  float m = fmaxf(fmaxf(tm[0][0], tm[0][1]), fmaxf(tm[0][2], tm[0][3]));
  m = fmaxf(m, __shfl_xor(m, 16));
  m = fmaxf(m, __shfl_xor(m, 32));

  // ---- exp2 + vector partial sums (two independent 8-chains)
  f32x4 uA = (f32x4){0.f, 0.f, 0.f, 0.f};
  f32x4 uB = (f32x4){0.f, 0.f, 0.f, 0.f};
  #pragma unroll
  for (int s = 0; s < 8; ++s) {
    #pragma unroll
    for (int j = 0; j < 4; ++j) {
      scA[s][j] = exp2f(scA[s][j] - m);
      scB[s][j] = exp2f(scB[s][j] - m);
    }
    uA += scA[s];
    uB += scB[s];
  }
  const f32x4 uv = uA + uB;
  float sum = (uv[0] + uv[1]) + (uv[2] + uv[3]);
  sum += __shfl_xor(sum, 16);
  sum += __shfl_xor(sum, 32);
  const float inv = 1.f / sum;

  // ---- pack normalized P (RNE) into K=32 A-fragments
  bf8 pa[8];
  #pragma unroll
  for (int s = 0; s < 8; ++s) {
    bf8 p;
    #pragma unroll
    for (int j = 0; j < 4; ++j) {
      p[j]     = (short)f2bf(scA[s][j] * inv);
      p[4 + j] = (short)f2bf(scB[s][j] * inv);
    }
    pa[s] = p;
  }

  // ---- PV: K=256 as 8 K=32 steps, 4 d-tiles
  f32x4 acc[4];
  #pragma unroll
  for (int ct = 0; ct < 4; ++ct) acc[ct] = (f32x4){0.f, 0.f, 0.f, 0.f};
  __builtin_amdgcn_s_setprio(1);
  #pragma unroll
  for (int s = 0; s < 8; ++s) {
    #pragma unroll
    for (int ct = 0; ct < 4; ++ct) {
      const bf8 vf = *(const bf8*)&Vs[(s * 4 + ct) * 512 + lane * 8];
      acc[ct] = __builtin_amdgcn_mfma_f32_16x16x32_bf16(pa[s], vf, acc[ct], 0, 0, 0);
    }
  }
  __builtin_amdgcn_s_setprio(0);

  // ---- ctx write: lane holds O[q=qrow+hi*4+j][d=h*64+ct*16+fr]
  #pragma unroll
  for (int ct = 0; ct < 4; ++ct)
    #pragma unroll
    for (int j = 0; j < 4; ++j)
      ctx[(size_t)(b * SEQ_ + qrow + hi * 4 + j) * DIM_ + h * HD_ + ct * 16 + fr] =
          f2bf(acc[ct][j]);
}

// ---------------------------------------------------------------------------
extern "C" void kernel_launch(void* const* d_in, const int* in_sizes, int n_in,
                              void* d_out, int out_size, void* d_ws, size_t ws_size,
                              hipStream_t stream) {
  const float* query = (const float*)d_in[0];
  const float* key   = (const float*)d_in[1];
  const float* value = (const float*)d_in[2];
  const float* mask  = (const float*)d_in[3];
  const float* Wq    = (const float*)d_in[4];
  const float* bq    = (const float*)d_in[5];
  const float* Wk    = (const float*)d_in[6];
  const float* bk    = (const float*)d_in[7];
  const float* Wv    = (const float*)d_in[8];
  const float* bv    = (const float*)d_in[9];
  const float* Wo    = (const float*)d_in[10];
  const float* bo    = (const float*)d_in[11];
  float* out = (float*)d_out;

  char* ws = (char*)d_ws;
  unsigned short* Qh  = (unsigned short*)ws;                  // 25,165,824 B
  unsigned short* ctx = (unsigned short*)(ws + 25165824);     // 25,165,824 B
  unsigned short* pK  = (unsigned short*)(ws + 50331648);     //  1,572,864 B
  unsigned short* pV  = (unsigned short*)(ws + 51904512);     //  1,572,864 B (pK+786432 elems)
  unsigned short* Kf  = (unsigned short*)(ws + 53477376);     //  1,572,864 B
  unsigned short* Vf  = (unsigned short*)(ws + 55050240);     //  1,572,864 B (Kf+786432 elems)
  float*          frac = (float*)(ws + 56623104);             //      4,096 B
  unsigned short* Wbf = (unsigned short*)(ws + 56627200);     //  4,718,592 B

  const float qscale = 0.125f * LOG2E;   // 1/sqrt(64), e->2 exponent base

  pool_kernel<<<dim3(1024), dim3(384), 0, stream>>>(key, value, mask, pK, pV, frac);
  cvtbf_kernel<<<dim3(1152), dim3(256), 0, stream>>>(Wq, Wk, Wv, Wo, Wbf);
  gemm_bt<1, 0, 1><<<dim3(768), dim3(256), 0, stream>>>(
      query, Wbf, bq, nullptr, nullptr, Qh, qscale);
  gemm_bt<0, 34, 0><<<dim3(8, 6, 2), dim3(256), 0, stream>>>(
      pK, Wbf + DIM_*DIM_, bk, bv, frac, Kf, 1.f);
  attn_fused<<<dim3(16, 48), dim3(1024), 0, stream>>>(Qh, Kf, Vf, ctx);
  gemm_bt<0, 2, 1><<<dim3(768), dim3(256), 0, stream>>>(
      ctx, Wbf + 3*DIM_*DIM_, bo, nullptr, nullptr, out, 1.f);
}